// Round 12
// baseline (399.132 us; speedup 1.0000x reference)
//
#include <hip/hip_runtime.h>
#include <hip/hip_bf16.h>
#include <cstdint>
#include <cstddef>
#include <math.h>

// GraphUNet forward on MI355X.
// Level-1 augment in fp8 e4m3 (integer entries: exact), K-interleaved rows
// for conflict-free b128 LDS reads, 64^2 tiles -> 1024 blocks; deeper levels
// bf16 splits. Fused augment+pool writes planes + transposes + row sums.
// Rank-based top-k with inline scores. dis computed inline from row sums.
// global_load_lds staging, counted-vmcnt pipelines in aug kernels.

#define DIVUP(a,b) (((a)+(b)-1)/(b))

using s16x8 = __attribute__((ext_vector_type(8))) short;
using f32x4 = __attribute__((ext_vector_type(4))) float;
using l64x2 = __attribute__((ext_vector_type(2))) long;

template<int N> __device__ __forceinline__ void waitvm() {
    if constexpr (N == 0)       asm volatile("s_waitcnt vmcnt(0)" ::: "memory");
    else if constexpr (N == 2)  asm volatile("s_waitcnt vmcnt(2)" ::: "memory");
    else if constexpr (N == 4)  asm volatile("s_waitcnt vmcnt(4)" ::: "memory");
    else if constexpr (N == 8)  asm volatile("s_waitcnt vmcnt(8)" ::: "memory");
    else                        asm volatile("s_waitcnt vmcnt(16)" ::: "memory");
}

__device__ __forceinline__ unsigned short f2bf(float v) {
    union { float f; unsigned u; } a; a.f = v;
    unsigned u = a.u;
    u = u + 0x7FFFu + ((u >> 16) & 1u);   // RNE
    return (unsigned short)(u >> 16);
}
__device__ __forceinline__ float bf2f(unsigned short h) {
    union { unsigned u; float f; } a; a.u = ((unsigned)h) << 16; return a.f;
}
__device__ __forceinline__ unsigned char f2e4m3(float v) {
    if (v <= 0.f) return 0;
    int e = 0; float m = v;
    while (m >= 2.f) { m *= 0.5f; ++e; }
    int mant = (int)(m * 8.f + 0.5f) - 8;
    if (mant >= 8) { mant = 0; ++e; }
    return (unsigned char)(((e + 7) << 3) | mant);
}
// K-interleave within 64-elem row: x = h*32 + kb*8 + e  ->  kb*16 + h*8 + e
__device__ __forceinline__ int perm64(int x) {
    return ((x >> 3) & 3) * 16 + ((x >> 5) & 1) * 8 + (x & 7);
}
__device__ __forceinline__ float disv(const float* dsum, const float* diag, int i) {
    float deg = dsum[i] + 1.0f + (diag ? diag[i] : 0.0f);
    return deg > 0.f ? 1.0f / sqrtf(deg) : 0.f;
}
__device__ __forceinline__ void gload_lds16(const unsigned short* g, unsigned short* l) {
    __builtin_amdgcn_global_load_lds(
        (const __attribute__((address_space(1))) void*)g,
        (__attribute__((address_space(3))) void*)l, 16, 0, 0);
}
__device__ __forceinline__ void gload_lds16b(const unsigned char* g, unsigned char* l) {
    __builtin_amdgcn_global_load_lds(
        (const __attribute__((address_space(1))) void*)g,
        (__attribute__((address_space(3))) void*)l, 16, 0, 0);
}

// ---------------- small kernels ----------------

__global__ void k_scatter(const int* __restrict__ e, float* __restrict__ A, int E, int n) {
    int t = blockIdx.x * blockDim.x + threadIdx.x;
    if (t < E) atomicAdd(&A[(size_t)e[t] * n + e[E + t]], 1.0f);
}

// plane (diag->1): bf16 + interleaved fp8 + fused row-sum
__global__ void k_a0_plane(const float* __restrict__ A, unsigned short* __restrict__ H,
                           unsigned char* __restrict__ F8,
                           float* __restrict__ d0, float* __restrict__ dsum, int n) {
    int t = blockIdx.x * 256 + threadIdx.x;
    int i = t / n, j = t - i * n;
    float v = A[t];
    if (i == j) { d0[i] = v; v = 1.0f; }
    H[t] = f2bf(v);
    F8[(size_t)i * n + (j & ~63) + perm64(j & 63)] = f2e4m3(v);
    __shared__ float red[256];
    red[threadIdx.x] = v; __syncthreads();
    for (int o = 128; o > 0; o >>= 1) {
        if (threadIdx.x < o) red[threadIdx.x] += red[threadIdx.x + o];
        __syncthreads();
    }
    if (threadIdx.x == 0) atomicAdd(&dsum[i], red[0]);
}

// interleaved-fp8 transpose: D[c][interleaved r] = A[r][c] (64x64 tiles)
__global__ void k_transpose_i8(const unsigned char* __restrict__ S, unsigned char* __restrict__ D, int n) {
    __shared__ unsigned char tile[64][65];
    int bx = blockIdx.x * 64, by = blockIdx.y * 64;
    const int tx = threadIdx.x & 63, ty = threadIdx.x >> 6;
    #pragma unroll
    for (int dy = 0; dy < 64; dy += 4)
        tile[ty + dy][tx] = S[(size_t)(by + ty + dy) * n + bx + perm64(tx)];
    __syncthreads();
    #pragma unroll
    for (int dy = 0; dy < 64; dy += 4)
        D[(size_t)(bx + ty + dy) * n + by + perm64(tx)] = tile[tx][ty + dy];
}

// stable rank under (score desc, idx asc) with INLINE scores (== jax.lax.top_k)
__global__ void k_count_rank(const float* __restrict__ x, const float* __restrict__ pv,
                             int* __restrict__ rank, int n) {
    __shared__ float pl[64];
    __shared__ float ls[256];
    if (threadIdx.x < 64) pl[threadIdx.x] = pv[threadIdx.x];
    __syncthreads();
    float n2 = 0.f;
    #pragma unroll
    for (int k = 0; k < 64; ++k) n2 += pl[k] * pl[k];
    const float nrm = sqrtf(n2);
    const int i = blockIdx.x * 256 + threadIdx.x;
    const int j = blockIdx.y * 256 + threadIdx.x;
    float sj = -INFINITY;
    if (j < n) {
        const float* xr = x + (size_t)j * 64;
        float d = 0.f;
        #pragma unroll
        for (int k = 0; k < 64; ++k) d += xr[k] * pl[k];
        sj = tanhf(d / nrm);
    }
    ls[threadIdx.x] = sj;
    __syncthreads();
    if (i >= n) return;
    float si;
    {
        const float* xr = x + (size_t)i * 64;
        float d = 0.f;
        #pragma unroll
        for (int k = 0; k < 64; ++k) d += xr[k] * pl[k];
        si = tanhf(d / nrm);
    }
    const int j0 = blockIdx.y * 256;
    int jj_n = n - j0; if (jj_n > 256) jj_n = 256;
    int cnt = 0;
    for (int jj = 0; jj < jj_n; ++jj) {
        float s2 = ls[jj];
        cnt += (s2 > si) || (s2 == si && (j0 + jj) < i);
    }
    atomicAdd(&rank[i], cnt);
}

// fused: perm[rank]=i, scout (inline score), pooled rows
__global__ void k_topk_finish(const float* __restrict__ x, const float* __restrict__ pv,
                              const int* __restrict__ rank, int n, int k, int kp,
                              int* __restrict__ perm, float* __restrict__ scout,
                              float* __restrict__ xo) {
    __shared__ float pl[64];
    if (threadIdx.x < 64) pl[threadIdx.x] = pv[threadIdx.x];
    __syncthreads();
    float n2 = 0.f;
    #pragma unroll
    for (int kq = 0; kq < 64; ++kq) n2 += pl[kq] * pl[kq];
    const float nrm = sqrtf(n2);
    int i = blockIdx.x * blockDim.x + threadIdx.x;
    if (i < n) {
        int r = rank[i];
        if (r < k) {
            const float* xr = x + (size_t)i * 64;
            float d = 0.f;
            #pragma unroll
            for (int kq = 0; kq < 64; ++kq) d += xr[kq] * pl[kq];
            float s = tanhf(d / nrm);
            perm[r] = i; scout[r] = s;
            float* xw = xo + (size_t)r * 64;
            #pragma unroll 8
            for (int f = 0; f < 64; ++f) xw[f] = xr[f] * s;
        }
    }
    if (i >= k && i < kp) { perm[i] = 0; scout[i] = 0.f; }
}

__global__ void k_unpool(const float* __restrict__ res, const float* __restrict__ xc,
                         const int* __restrict__ rank, float* __restrict__ o, int n, int k) {
    int t = blockIdx.x * blockDim.x + threadIdx.x;
    if (t >= n * 64) return;
    int r = rank[t >> 6];
    o[t] = res[t] + (r < k ? xc[(size_t)r * 64 + (t & 63)] : 0.f);
}

// XW = x@W ; Y = dis*XW (dis inline from dsum) ; Yt = 3-way bf16 split of Y^T
__global__ void k_xw(const float* __restrict__ x, const float* __restrict__ W,
                     const float* __restrict__ dsum, const float* __restrict__ diag,
                     int n, int np, int cin, int ldw, int nout,
                     float* __restrict__ Y, unsigned short* __restrict__ T0,
                     unsigned short* __restrict__ T1, unsigned short* __restrict__ T2) {
    int t = blockIdx.x * blockDim.x + threadIdx.x;
    if (t >= np * 64) return;
    int i = t >> 6, f = t & 63;
    float y = 0.f;
    if (i < n && f < nout) {
        float a = 0.f;
        for (int k = 0; k < cin; ++k) a += x[(size_t)i * cin + k] * W[(size_t)k * ldw + f];
        y = disv(dsum, diag, i) * a;
    }
    Y[t] = y;
    unsigned short h0 = f2bf(y);
    float r1 = y - bf2f(h0);
    unsigned short h1 = f2bf(r1);
    float r2 = r1 - bf2f(h1);
    size_t ti = (size_t)f * np + i;
    T0[ti] = h0; T1[ti] = h1; T2[ti] = f2bf(r2);
}

// ---------------- MFMA GEMMs ----------------

// fp8 fused augment+pool (level 1): TM*32 tile; one b128/lane/row (both
// K-halves via the interleave), slot = kb ^ ((row>>1)&3).
template<int TM>
__global__ __launch_bounds__(256) void k_aug8(
    const unsigned char* __restrict__ P8, const unsigned char* __restrict__ Q8,
    const int* __restrict__ perm, int kk, int kp, int K, int ns,
    unsigned short* __restrict__ H0, unsigned short* __restrict__ T0,
    float* __restrict__ dsum)
{
    constexpr int BM = TM * 32;
    constexpr int PS = BM * 64;
    constexpr int D = 3;
    constexpr int STG = 2 * PS;
    constexpr int LPP = TM / 2;
    constexpr int LPS = 2 * LPP;
    constexpr int TRE = BM * (BM + 2) * 2;
    constexpr int SMEB = (D * STG > TRE) ? D * STG : TRE;
    __shared__ __align__(16) unsigned char smem[SMEB];
    const int tid = threadIdx.x, lane = tid & 63;
    const int wm = tid >> 7, wn = (tid >> 6) & 1;
    const int bm = blockIdx.x * BM, bn = blockIdx.y * BM;
    const unsigned char* spA[LPP];
    const unsigned char* spB[LPP];
    int dstb[LPP];
    #pragma unroll
    for (int it = 0; it < LPP; ++it) {
        int s = tid + it * 256;
        int row = s >> 2, c = (s & 3) ^ ((row >> 1) & 3);
        dstb[it] = (s - lane) * 16;
        spA[it] = P8 + (size_t)perm[bm + row] * ns + 16 * c;
        spB[it] = Q8 + (size_t)perm[bn + row] * ns + 16 * c;
    }
    f32x4 acc[TM][TM] = {};
    const int l15 = lane & 15, kb = lane >> 4;
    const int nt = K >> 6;

    auto stage = [&](int b, int koff) {
        unsigned char* base = smem + b * STG;
        #pragma unroll
        for (int it = 0; it < LPP; ++it) gload_lds16b(spA[it] + koff, base + dstb[it]);
        #pragma unroll
        for (int it = 0; it < LPP; ++it) gload_lds16b(spB[it] + koff, base + PS + dstb[it]);
    };
    auto compute = [&](int b) {
        const unsigned char* base = smem + b * STG;
        l64x2 av[TM], bv[TM];
        #pragma unroll
        for (int mi = 0; mi < TM; ++mi) {
            int row = wm * (TM * 16) + mi * 16 + l15;
            int slot = kb ^ ((row >> 1) & 3);
            av[mi] = *(const l64x2*)(base + row * 64 + slot * 16);
        }
        #pragma unroll
        for (int ni = 0; ni < TM; ++ni) {
            int row = wn * (TM * 16) + ni * 16 + l15;
            int slot = kb ^ ((row >> 1) & 3);
            bv[ni] = *(const l64x2*)(base + PS + row * 64 + slot * 16);
        }
        #pragma unroll
        for (int h = 0; h < 2; ++h)
            #pragma unroll
            for (int mi = 0; mi < TM; ++mi)
                #pragma unroll
                for (int ni = 0; ni < TM; ++ni)
                    acc[mi][ni] = __builtin_amdgcn_mfma_f32_16x16x32_fp8_fp8(
                        av[mi][h], bv[ni][h], acc[mi][ni], 0, 0, 0);
    };

    stage(0, 0); stage(1, 64);
    for (int t = 0; t < nt; ++t) {
        const int ahead = nt - 1 - t;
        if (ahead >= D - 1) {
            stage((t + D - 1) % D, (t + D - 1) * 64);
            waitvm<2 * LPS>();
        } else if (ahead == 1) {
            waitvm<LPS>();
        } else {
            waitvm<0>();
        }
        __builtin_amdgcn_sched_barrier(0);
        __builtin_amdgcn_s_barrier();
        compute(t % D);
        __builtin_amdgcn_s_barrier();
    }

    const int hi = lane >> 4;
    #pragma unroll
    for (int mi = 0; mi < TM; ++mi)
        #pragma unroll
        for (int r = 0; r < 4; ++r) {
            int row = bm + wm * (TM * 16) + mi * 16 + hi * 4 + r;
            float s = 0.f;
            #pragma unroll
            for (int ni = 0; ni < TM; ++ni) {
                int col = bn + wn * (TM * 16) + ni * 16 + l15;
                float v = (row < kk && col < kk) ? ((row == col) ? 1.f : acc[mi][ni][r]) : 0.f;
                H0[(size_t)row * kp + col] = f2bf(v);
                s += v;
            }
            #pragma unroll
            for (int m = 1; m < 16; m <<= 1) s += __shfl_xor(s, m);
            if (l15 == 0) atomicAdd(&dsum[row], s);
        }

    unsigned short* smw = (unsigned short*)smem;
    __syncthreads();
    #pragma unroll
    for (int mi = 0; mi < TM; ++mi)
        #pragma unroll
        for (int ni = 0; ni < TM; ++ni)
            #pragma unroll
            for (int r = 0; r < 4; ++r) {
                int rl = wm * (TM * 16) + mi * 16 + hi * 4 + r;
                int cl = wn * (TM * 16) + ni * 16 + l15;
                int row = bm + rl, col = bn + cl;
                float v = (row < kk && col < kk) ? ((row == col) ? 1.f : acc[mi][ni][r]) : 0.f;
                smw[rl * (BM + 2) + cl] = f2bf(v);
            }
    __syncthreads();
    #pragma unroll
    for (int e = 0; e < BM * BM / 256; ++e) {
        int idx = tid + e * 256;
        int j = idx / BM, i = idx & (BM - 1);
        T0[(size_t)(bn + j) * kp + (bm + i)] = smw[i * (BM + 2) + j];
    }
}

// bf16 fused augment+pool+split (levels 2-3)
template<int TM, int PA, int PB, int NP, int NT>
__global__ __launch_bounds__(256) void k_aug2(
    const unsigned short* __restrict__ Pa, const unsigned short* __restrict__ Pb,
    const unsigned short* __restrict__ Qa, const unsigned short* __restrict__ Qb,
    const int* __restrict__ perm, int kk, int kp, int K, int ns,
    unsigned short* __restrict__ H0, unsigned short* __restrict__ H1,
    unsigned short* __restrict__ H2,
    unsigned short* __restrict__ T0, unsigned short* __restrict__ T1,
    float* __restrict__ dsum)
{
    constexpr int BM  = TM * 32;
    constexpr int PS  = TM * 2048;
    constexpr int D   = 3;
    constexpr int STG = (PA + PB) * PS;
    constexpr int LPS = TM * (PA + PB);
    constexpr int TRE = NT ? (BM * (BM + 2)) : 0;
    constexpr int SME = (D * STG > TRE) ? (D * STG) : TRE;
    __shared__ __align__(16) unsigned short smem[SME];
    const int tid = threadIdx.x, lane = tid & 63;
    const int wm = tid >> 7, wn = (tid >> 6) & 1;
    const int bm = blockIdx.x * BM, bn = blockIdx.y * BM;
    const unsigned short* P[2] = {Pa, Pb};
    const unsigned short* Q[2] = {Qa, Qb};
    const unsigned short* sp[PA][TM];
    const unsigned short* sq[PB][TM];
    int dst[TM];
    #pragma unroll
    for (int it = 0; it < TM; ++it) {
        int s = tid + it * 256;
        int row = s >> 3, c = (s & 7) ^ (row & 7);
        dst[it] = (s - lane) * 8;
        #pragma unroll
        for (int p = 0; p < PA; ++p)
            sp[p][it] = P[p] + (size_t)perm[bm + row] * ns + 8 * c;
        #pragma unroll
        for (int p = 0; p < PB; ++p)
            sq[p][it] = Q[p] + (size_t)perm[bn + row] * ns + 8 * c;
    }
    f32x4 acc[TM][TM] = {};
    const int l15 = lane & 15, kb = lane >> 4;
    const int nt = K >> 6;

    auto stage = [&](int b, int koff) {
        unsigned short* base = smem + b * STG;
        #pragma unroll
        for (int p = 0; p < PA; ++p)
            #pragma unroll
            for (int it = 0; it < TM; ++it)
                gload_lds16(sp[p][it] + koff, base + p * PS + dst[it]);
        #pragma unroll
        for (int p = 0; p < PB; ++p)
            #pragma unroll
            for (int it = 0; it < TM; ++it)
                gload_lds16(sq[p][it] + koff, base + PA * PS + p * PS + dst[it]);
    };
    auto compute = [&](int b) {
        const unsigned short* base = smem + b * STG;
        #pragma unroll
        for (int h = 0; h < 2; ++h) {
            s16x8 av[PA][TM], bv[PB][TM];
            #pragma unroll
            for (int p = 0; p < PA; ++p)
                #pragma unroll
                for (int mi = 0; mi < TM; ++mi) {
                    int row = wm * (TM * 16) + mi * 16 + l15;
                    int slot = (h * 4 + kb) ^ (row & 7);
                    av[p][mi] = *(const s16x8*)(base + p * PS + row * 64 + slot * 8);
                }
            #pragma unroll
            for (int p = 0; p < PB; ++p)
                #pragma unroll
                for (int ni = 0; ni < TM; ++ni) {
                    int row = wn * (TM * 16) + ni * 16 + l15;
                    int slot = (h * 4 + kb) ^ (row & 7);
                    bv[p][ni] = *(const s16x8*)(base + PA * PS + p * PS + row * 64 + slot * 8);
                }
            #pragma unroll
            for (int mi = 0; mi < TM; ++mi)
                #pragma unroll
                for (int ni = 0; ni < TM; ++ni)
                    #pragma unroll
                    for (int pa = 0; pa < PA; ++pa)
                        #pragma unroll
                        for (int pb = 0; pb < PB; ++pb)
                            acc[mi][ni] = __builtin_amdgcn_mfma_f32_16x16x32_bf16(
                                av[pa][mi], bv[pb][ni], acc[mi][ni], 0, 0, 0);
        }
    };

    for (int i = 0; i < D - 1; ++i) stage(i, i * 64);
    for (int t = 0; t < nt; ++t) {
        const int ahead = nt - 1 - t;
        if (ahead >= D - 1) {
            stage((t + D - 1) % D, (t + D - 1) * 64);
            waitvm<2 * LPS>();
        } else if (ahead == 1) {
            waitvm<LPS>();
        } else {
            waitvm<0>();
        }
        __builtin_amdgcn_sched_barrier(0);
        __builtin_amdgcn_s_barrier();
        compute(t % D);
        __builtin_amdgcn_s_barrier();
    }

    const int hi = lane >> 4;
    #pragma unroll
    for (int mi = 0; mi < TM; ++mi)
        #pragma unroll
        for (int r = 0; r < 4; ++r) {
            int row = bm + wm * (TM * 16) + mi * 16 + hi * 4 + r;
            float s = 0.f;
            #pragma unroll
            for (int ni = 0; ni < TM; ++ni) {
                int col = bn + wn * (TM * 16) + ni * 16 + l15;
                float v = (row < kk && col < kk) ? ((row == col) ? 1.f : acc[mi][ni][r]) : 0.f;
                s += v;
                unsigned short h0 = f2bf(v);
                size_t o = (size_t)row * kp + col;
                H0[o] = h0;
                if (NP > 1) {
                    float r1 = v - bf2f(h0);
                    unsigned short h1 = f2bf(r1);
                    H1[o] = h1;
                    if (NP > 2) H2[o] = f2bf(r1 - bf2f(h1));
                }
            }
            #pragma unroll
            for (int m = 1; m < 16; m <<= 1) s += __shfl_xor(s, m);
            if (l15 == 0) atomicAdd(&dsum[row], s);
        }

    if (NT > 0) {
        #pragma unroll
        for (int pass = 0; pass < NT; ++pass) {
            __syncthreads();
            #pragma unroll
            for (int mi = 0; mi < TM; ++mi)
                #pragma unroll
                for (int ni = 0; ni < TM; ++ni)
                    #pragma unroll
                    for (int r = 0; r < 4; ++r) {
                        int rl = wm * (TM * 16) + mi * 16 + hi * 4 + r;
                        int cl = wn * (TM * 16) + ni * 16 + l15;
                        int row = bm + rl, col = bn + cl;
                        float v = (row < kk && col < kk) ? ((row == col) ? 1.f : acc[mi][ni][r]) : 0.f;
                        unsigned short h0 = f2bf(v);
                        unsigned short hv = h0;
                        if (pass == 1) hv = f2bf(v - bf2f(h0));
                        smem[rl * (BM + 2) + cl] = hv;
                    }
            __syncthreads();
            unsigned short* T = pass ? T1 : T0;
            #pragma unroll
            for (int e = 0; e < BM * BM / 256; ++e) {
                int idx = tid + e * 256;
                int j = idx / BM, i = idx & (BM - 1);
                T[(size_t)(bn + j) * kp + (bm + i)] = smem[i * (BM + 2) + j];
            }
        }
    }
}

template<int PA>
__global__ __launch_bounds__(256) void k_gcn_gemm(
    const unsigned short* __restrict__ Aa, const unsigned short* __restrict__ Ab,
    const unsigned short* __restrict__ Ac,
    const unsigned short* __restrict__ B0, const unsigned short* __restrict__ B1,
    const unsigned short* __restrict__ B2,
    int np, int kchunk, float* __restrict__ Zp)
{
    __shared__ __align__(16) unsigned short la[PA * 4096];
    __shared__ __align__(16) unsigned short lb[3 * 4096];
    const int tid = threadIdx.x, lane = tid & 63, wv = tid >> 6;
    const int bm = blockIdx.x * 64;
    const int kbeg = blockIdx.y * kchunk;
    const unsigned short* A[3] = {Aa, Ab, Ac};
    const unsigned short* B[3] = {B0, B1, B2};
    const unsigned short* sa[PA][2];
    const unsigned short* sb[3][2];
    int dst[2];
    #pragma unroll
    for (int it = 0; it < 2; ++it) {
        int s = tid + it * 256;
        int row = s >> 3, c = (s & 7) ^ (row & 7);
        dst[it] = (s - lane) * 8;
        #pragma unroll
        for (int p = 0; p < PA; ++p)
            sa[p][it] = A[p] + (size_t)(bm + row) * np + kbeg + 8 * c;
        #pragma unroll
        for (int p = 0; p < 3; ++p)
            sb[p][it] = B[p] + (size_t)row * np + kbeg + 8 * c;
    }
    f32x4 acc[4] = {};
    const int l15 = lane & 15, kb = lane >> 4;
    const int nt = kchunk >> 6;

    for (int tt = 0; tt < nt; ++tt) {
        if (tt) __syncthreads();
        int koff = tt * 64;
        #pragma unroll
        for (int p = 0; p < PA; ++p)
            #pragma unroll
            for (int it = 0; it < 2; ++it)
                gload_lds16(sa[p][it] + koff, &la[p * 4096 + dst[it]]);
        #pragma unroll
        for (int p = 0; p < 3; ++p)
            #pragma unroll
            for (int it = 0; it < 2; ++it)
                gload_lds16(sb[p][it] + koff, &lb[p * 4096 + dst[it]]);
        __syncthreads();
        #pragma unroll
        for (int h = 0; h < 2; ++h) {
            s16x8 av[PA], bv[3][4];
            #pragma unroll
            for (int p = 0; p < PA; ++p) {
                int row = wv * 16 + l15;
                int slot = (h * 4 + kb) ^ (row & 7);
                av[p] = *(const s16x8*)&la[p * 4096 + row * 64 + slot * 8];
            }
            #pragma unroll
            for (int p = 0; p < 3; ++p)
                #pragma unroll
                for (int ni = 0; ni < 4; ++ni) {
                    int row = ni * 16 + l15;
                    int slot = (h * 4 + kb) ^ (row & 7);
                    bv[p][ni] = *(const s16x8*)&lb[p * 4096 + row * 64 + slot * 8];
                }
            #pragma unroll
            for (int ni = 0; ni < 4; ++ni)
                #pragma unroll
                for (int pa = 0; pa < PA; ++pa)
                    #pragma unroll
                    for (int pb = 0; pb <= 2 - pa; ++pb)
                        acc[ni] = __builtin_amdgcn_mfma_f32_16x16x32_bf16(
                            av[pa], bv[pb][ni], acc[ni], 0, 0, 0);
        }
    }

    const int l4 = lane >> 4;
    float* Z = Zp + (size_t)blockIdx.y * np * 64;
    for (int ni = 0; ni < 4; ++ni)
        #pragma unroll
        for (int r = 0; r < 4; ++r) {
            int row = bm + wv * 16 + l4 * 4 + r;
            Z[(size_t)row * 64 + ni * 16 + l15] = acc[ni][r];
        }
}

// out = relu?( dis_i * (sum_ksplit Z + (diag_true+1)*Y_i) + b ), dis inline
__global__ void k_gcn_epi(const float* __restrict__ Zp, const float* __restrict__ Y,
                          const float* __restrict__ dsum, const float* __restrict__ diagv,
                          const float* __restrict__ b, int n, int np, int nout, int relu,
                          int S, float* __restrict__ xo) {
    int t = blockIdx.x * blockDim.x + threadIdx.x;
    if (t >= n * 64) return;
    int i = t >> 6, f = t & 63;
    float s = 0.f;
    for (int kq = 0; kq < S; ++kq) s += Zp[(size_t)kq * np * 64 + t];
    float coef = 1.f + (diagv ? diagv[i] : 0.f);
    float v = disv(dsum, diagv, i) * (s + coef * Y[t]) + (f < nout ? b[f] : 0.f);
    if (relu) v = fmaxf(v, 0.f);
    xo[t] = v;
}

__global__ void k_softmax(const float* __restrict__ lg, float* __restrict__ o, int n) {
    int i = blockIdx.x * blockDim.x + threadIdx.x;
    if (i >= n) return;
    float a = lg[i * 64], b = lg[i * 64 + 1], c = lg[i * 64 + 2];
    float m = fmaxf(a, fmaxf(b, c));
    float ea = expf(a - m), eb = expf(b - m), ec = expf(c - m);
    float s = ea + eb + ec;
    o[i * 3] = ea / s; o[i * 3 + 1] = eb / s; o[i * 3 + 2] = ec / s;
}

// ---------------- launch ----------------

extern "C" void kernel_launch(void* const* d_in, const int* in_sizes, int n_in,
                              void* d_out, int out_size, void* d_ws, size_t ws_size,
                              hipStream_t stream) {
    const int N0 = 3072;
    const int E = in_sizes[1] / 2;
    const int CIN = in_sizes[0] / N0;

    const float* x_in = (const float*)d_in[0];
    const int*   eidx = (const int*)d_in[1];
    const float* Wd0 = (const float*)d_in[2];  const float* bd0 = (const float*)d_in[3];
    const float* Wd1 = (const float*)d_in[4];  const float* bd1 = (const float*)d_in[5];
    const float* Wd2 = (const float*)d_in[6];  const float* bd2 = (const float*)d_in[7];
    const float* Wd3 = (const float*)d_in[8];  const float* bd3 = (const float*)d_in[9];
    const float* p1  = (const float*)d_in[10]; const float* p2  = (const float*)d_in[11];
    const float* p3  = (const float*)d_in[12];
    const float* Wu0 = (const float*)d_in[13]; const float* bu0 = (const float*)d_in[14];
    const float* Wu1 = (const float*)d_in[15]; const float* bu1 = (const float*)d_in[16];
    const float* Wu2 = (const float*)d_in[17]; const float* bu2 = (const float*)d_in[18];
    float* out = (float*)d_out;

    char* ws = (char*)d_ws;
    size_t off = 0;
    auto alloc = [&](size_t bytes) -> void* {
        off = (off + 255) & ~(size_t)255;
        void* p = ws + off;
        off += bytes;
        return p;
    };

    unsigned short* A0H  = (unsigned short*)alloc((size_t)3072 * 3072 * 2);
    unsigned char*  A0F8 = (unsigned char*)alloc((size_t)3072 * 3072);
    unsigned char*  A0T8 = (unsigned char*)alloc((size_t)3072 * 3072);
    float* d0   = (float*)alloc(3072 * 4);
    float* x0   = (float*)alloc((size_t)3072 * 64 * 4);
    unsigned short* P1H = (unsigned short*)alloc((size_t)2048 * 2048 * 2);
    unsigned short* P1T = (unsigned short*)alloc((size_t)2048 * 2048 * 2);
    float* x1   = (float*)alloc((size_t)2048 * 64 * 4);
    float* xp1  = (float*)alloc((size_t)2048 * 64 * 4);
    unsigned short* P2H  = (unsigned short*)alloc((size_t)1024 * 1024 * 2);
    unsigned short* P2L  = (unsigned short*)alloc((size_t)1024 * 1024 * 2);
    unsigned short* P2TH = (unsigned short*)alloc((size_t)1024 * 1024 * 2);
    unsigned short* P2TL = (unsigned short*)alloc((size_t)1024 * 1024 * 2);
    float* x2   = (float*)alloc((size_t)1024 * 64 * 4);
    float* xp2  = (float*)alloc((size_t)1024 * 64 * 4);
    unsigned short* P3a = (unsigned short*)alloc((size_t)512 * 512 * 2);
    unsigned short* P3b = (unsigned short*)alloc((size_t)512 * 512 * 2);
    unsigned short* P3c = (unsigned short*)alloc((size_t)512 * 512 * 2);
    float* x3   = (float*)alloc((size_t)512 * 64 * 4);
    float* xp3  = (float*)alloc((size_t)512 * 64 * 4);
    int*   perm1 = (int*)alloc(2048 * 4);  float* sc1 = (float*)alloc(2048 * 4);
    int*   perm2 = (int*)alloc(1024 * 4);  float* sc2 = (float*)alloc(1024 * 4);
    int*   perm3 = (int*)alloc(512 * 4);   float* sc3 = (float*)alloc(512 * 4);
    // zeroed-each-launch region: dsum0..3 + rank1..3 contiguous (one memset)
    float* dsum0 = (float*)alloc(3072 * 4);
    float* dsum1 = (float*)alloc(2048 * 4);
    float* dsum2 = (float*)alloc(1024 * 4);
    float* dsum3 = (float*)alloc(512 * 4);
    int* rank1 = (int*)alloc(3072 * 4);
    int* rank2 = (int*)alloc(2048 * 4);
    int* rank3 = (int*)alloc(1024 * 4);
    float* Yf  = (float*)alloc((size_t)3072 * 64 * 4);
    unsigned short* Yt0 = (unsigned short*)alloc((size_t)64 * 3072 * 2);
    unsigned short* Yt1 = (unsigned short*)alloc((size_t)64 * 3072 * 2);
    unsigned short* Yt2 = (unsigned short*)alloc((size_t)64 * 3072 * 2);
    float* Zp   = (float*)alloc((size_t)16 * 3072 * 64 * 4);
    float* xlog = (float*)alloc((size_t)3072 * 64 * 4);
    float* t2b  = (float*)alloc((size_t)1024 * 64 * 4);
    float* t1b  = (float*)alloc((size_t)2048 * 64 * 4);
    float* t0b  = (float*)alloc((size_t)3072 * 64 * 4);
    char* scratch = (char*)alloc((size_t)3072 * 3072 * 4);
    if (off > ws_size) return;

    float* A0f = (float*)scratch;

    auto gcn = [&](const float* xin, int cin, const float* W, int ldw, int nout, const float* bias,
                   const unsigned short* Pa, const unsigned short* Pb2, const unsigned short* Pc,
                   int PA, int n, int np2, const float* dsum, const float* diagv, int relu, float* xout) {
        k_xw<<<DIVUP(np2 * 64, 256), 256, 0, stream>>>(xin, W, dsum, diagv, n, np2, cin, ldw, nout, Yf, Yt0, Yt1, Yt2);
        int S = (np2 >= 1024) ? 16 : 8;
        int kch = np2 / S;
        dim3 gg(np2 / 64, S);
        if (PA == 1)      k_gcn_gemm<1><<<gg, 256, 0, stream>>>(Pa, Pa, Pa, Yt0, Yt1, Yt2, np2, kch, Zp);
        else if (PA == 2) k_gcn_gemm<2><<<gg, 256, 0, stream>>>(Pa, Pb2, Pb2, Yt0, Yt1, Yt2, np2, kch, Zp);
        else              k_gcn_gemm<3><<<gg, 256, 0, stream>>>(Pa, Pb2, Pc, Yt0, Yt1, Yt2, np2, kch, Zp);
        k_gcn_epi<<<DIVUP(n * 64, 256), 256, 0, stream>>>(Zp, Yf, dsum, diagv, bias, n, np2, nout, relu, S, xout);
    };

    auto topk = [&](const float* x, const float* pvec, int n, int k, int kp,
                    int* rank, int* perm, float* scv, float* xo) {
        dim3 gr(DIVUP(n, 256), DIVUP(n, 256));
        k_count_rank<<<gr, 256, 0, stream>>>(x, pvec, rank, n);
        k_topk_finish<<<DIVUP(n, 256), 256, 0, stream>>>(x, pvec, rank, n, k, kp, perm, scv, xo);
    };

    hipMemsetAsync(dsum0, 0, (char*)(rank3 + 1024) - (char*)dsum0, stream);

    hipMemsetAsync(A0f, 0, (size_t)3072 * 3072 * 4, stream);
    k_scatter<<<DIVUP(E, 256), 256, 0, stream>>>(eidx, A0f, E, N0);
    k_a0_plane<<<3072 * 3072 / 256, 256, 0, stream>>>(A0f, A0H, A0F8, d0, dsum0, N0);
    k_transpose_i8<<<dim3(48, 48), 256, 0, stream>>>(A0F8, A0T8, 3072);

    gcn(x_in, CIN, Wd0, 64, 64, bd0, A0H, A0H, A0H, 1, 3072, 3072, dsum0, d0, 1, x0);

    topk(x0, p1, 3072, 2000, 2048, rank1, perm1, sc1, xp1);
    k_aug8<2><<<dim3(32, 32), 256, 0, stream>>>(
        A0F8, A0T8, perm1, 2000, 2048, 3072, 3072, P1H, P1T, dsum1);
    gcn(xp1, 64, Wd1, 64, 64, bd1, P1H, P1H, P1H, 1, 2000, 2048, dsum1, nullptr, 1, x1);

    topk(x1, p2, 2000, 1000, 1024, rank2, perm2, sc2, xp2);
    k_aug2<2, 1, 1, 2, 2><<<dim3(16, 16), 256, 0, stream>>>(
        P1H, P1H, P1T, P1T, perm2, 1000, 1024, 2048, 2048, P2H, P2L, P2L, P2TH, P2TL, dsum2);
    gcn(xp2, 64, Wd2, 64, 64, bd2, P2H, P2L, P2L, 2, 1000, 1024, dsum2, nullptr, 1, x2);

    topk(x2, p3, 1000, 500, 512, rank3, perm3, sc3, xp3);
    k_aug2<2, 2, 2, 3, 0><<<dim3(8, 8), 256, 0, stream>>>(
        P2H, P2L, P2TH, P2TL, perm3, 500, 512, 1024, 1024, P3a, P3b, P3c, nullptr, nullptr, dsum3);
    gcn(xp3, 64, Wd3, 64, 64, bd3, P3a, P3b, P3c, 3, 500, 512, dsum3, nullptr, 1, x3);

    k_unpool<<<DIVUP(1000 * 64, 256), 256, 0, stream>>>(x2, x3, rank3, t2b, 1000, 500);
    gcn(t2b, 64, Wu0, 64, 64, bu0, P2H, P2L, P2L, 2, 1000, 1024, dsum2, nullptr, 1, xp2);

    k_unpool<<<DIVUP(2000 * 64, 256), 256, 0, stream>>>(x1, xp2, rank2, t1b, 2000, 1000);
    gcn(t1b, 64, Wu1, 64, 64, bu1, P1H, P1H, P1H, 1, 2000, 2048, dsum1, nullptr, 1, xp1);

    k_unpool<<<DIVUP(3072 * 64, 256), 256, 0, stream>>>(x0, xp1, rank1, t0b, 3072, 2000);
    gcn(t0b, 64, Wu2, 3, 3, bu2, A0H, A0H, A0H, 1, 3072, 3072, dsum0, d0, 0, xlog);

    k_softmax<<<DIVUP(3072, 256), 256, 0, stream>>>(xlog, out, 3072);
}

// Round 13
// 384.650 us; speedup vs baseline: 1.0376x; 1.0376x over previous
//
#include <hip/hip_runtime.h>
#include <hip/hip_bf16.h>
#include <cstdint>
#include <cstddef>
#include <math.h>

// GraphUNet forward on MI355X.
// Level-1 augment in fp8 e4m3 (integer entries: exact), K-interleaved rows
// for conflict-free b128 LDS reads, 64^2 tiles; deeper levels bf16 splits.
// Fused augment+pool writes planes + transposes + row sums. Rank-based
// top-k with inline scores; unpool fused into xw; softmax fused into the
// final epilogue. global_load_lds staging, counted-vmcnt pipelines.

#define DIVUP(a,b) (((a)+(b)-1)/(b))

using s16x8 = __attribute__((ext_vector_type(8))) short;
using f32x4 = __attribute__((ext_vector_type(4))) float;
using l64x2 = __attribute__((ext_vector_type(2))) long;

template<int N> __device__ __forceinline__ void waitvm() {
    if constexpr (N == 0)       asm volatile("s_waitcnt vmcnt(0)" ::: "memory");
    else if constexpr (N == 2)  asm volatile("s_waitcnt vmcnt(2)" ::: "memory");
    else if constexpr (N == 4)  asm volatile("s_waitcnt vmcnt(4)" ::: "memory");
    else if constexpr (N == 8)  asm volatile("s_waitcnt vmcnt(8)" ::: "memory");
    else                        asm volatile("s_waitcnt vmcnt(16)" ::: "memory");
}

__device__ __forceinline__ unsigned short f2bf(float v) {
    union { float f; unsigned u; } a; a.f = v;
    unsigned u = a.u;
    u = u + 0x7FFFu + ((u >> 16) & 1u);   // RNE
    return (unsigned short)(u >> 16);
}
__device__ __forceinline__ float bf2f(unsigned short h) {
    union { unsigned u; float f; } a; a.u = ((unsigned)h) << 16; return a.f;
}
__device__ __forceinline__ unsigned char f2e4m3(float v) {
    if (v <= 0.f) return 0;
    int e = 0; float m = v;
    while (m >= 2.f) { m *= 0.5f; ++e; }
    int mant = (int)(m * 8.f + 0.5f) - 8;
    if (mant >= 8) { mant = 0; ++e; }
    return (unsigned char)(((e + 7) << 3) | mant);
}
// K-interleave within 64-elem row: x = h*32 + kb*8 + e  ->  kb*16 + h*8 + e
__device__ __forceinline__ int perm64(int x) {
    return ((x >> 3) & 3) * 16 + ((x >> 5) & 1) * 8 + (x & 7);
}
__device__ __forceinline__ float disv(const float* dsum, const float* diag, int i) {
    float deg = dsum[i] + 1.0f + (diag ? diag[i] : 0.0f);
    return deg > 0.f ? 1.0f / sqrtf(deg) : 0.f;
}
__device__ __forceinline__ void gload_lds16(const unsigned short* g, unsigned short* l) {
    __builtin_amdgcn_global_load_lds(
        (const __attribute__((address_space(1))) void*)g,
        (__attribute__((address_space(3))) void*)l, 16, 0, 0);
}
__device__ __forceinline__ void gload_lds16b(const unsigned char* g, unsigned char* l) {
    __builtin_amdgcn_global_load_lds(
        (const __attribute__((address_space(1))) void*)g,
        (__attribute__((address_space(3))) void*)l, 16, 0, 0);
}

// ---------------- small kernels ----------------

__global__ void k_scatter(const int* __restrict__ e, float* __restrict__ A, int E, int n) {
    int t = blockIdx.x * blockDim.x + threadIdx.x;
    if (t < E) atomicAdd(&A[(size_t)e[t] * n + e[E + t]], 1.0f);
}

// plane (diag->1): bf16 + interleaved fp8 + fused row-sum
__global__ void k_a0_plane(const float* __restrict__ A, unsigned short* __restrict__ H,
                           unsigned char* __restrict__ F8,
                           float* __restrict__ d0, float* __restrict__ dsum, int n) {
    int t = blockIdx.x * 256 + threadIdx.x;
    int i = t / n, j = t - i * n;
    float v = A[t];
    if (i == j) { d0[i] = v; v = 1.0f; }
    H[t] = f2bf(v);
    F8[(size_t)i * n + (j & ~63) + perm64(j & 63)] = f2e4m3(v);
    __shared__ float red[256];
    red[threadIdx.x] = v; __syncthreads();
    for (int o = 128; o > 0; o >>= 1) {
        if (threadIdx.x < o) red[threadIdx.x] += red[threadIdx.x + o];
        __syncthreads();
    }
    if (threadIdx.x == 0) atomicAdd(&dsum[i], red[0]);
}

// interleaved-fp8 transpose: D[c][interleaved r] = A[r][c] (64x64 tiles)
__global__ void k_transpose_i8(const unsigned char* __restrict__ S, unsigned char* __restrict__ D, int n) {
    __shared__ unsigned char tile[64][65];
    int bx = blockIdx.x * 64, by = blockIdx.y * 64;
    const int tx = threadIdx.x & 63, ty = threadIdx.x >> 6;
    #pragma unroll
    for (int dy = 0; dy < 64; dy += 4)
        tile[ty + dy][tx] = S[(size_t)(by + ty + dy) * n + bx + perm64(tx)];
    __syncthreads();
    #pragma unroll
    for (int dy = 0; dy < 64; dy += 4)
        D[(size_t)(bx + ty + dy) * n + by + perm64(tx)] = tile[tx][ty + dy];
}

// stable rank under (score desc, idx asc) with INLINE scores (== jax.lax.top_k)
__global__ void k_count_rank(const float* __restrict__ x, const float* __restrict__ pv,
                             int* __restrict__ rank, int n) {
    __shared__ float pl[64];
    __shared__ float ls[256];
    if (threadIdx.x < 64) pl[threadIdx.x] = pv[threadIdx.x];
    __syncthreads();
    float n2 = 0.f;
    #pragma unroll
    for (int k = 0; k < 64; ++k) n2 += pl[k] * pl[k];
    const float nrm = sqrtf(n2);
    const int i = blockIdx.x * 256 + threadIdx.x;
    const int j = blockIdx.y * 256 + threadIdx.x;
    float sj = -INFINITY;
    if (j < n) {
        const float* xr = x + (size_t)j * 64;
        float d = 0.f;
        #pragma unroll
        for (int k = 0; k < 64; ++k) d += xr[k] * pl[k];
        sj = tanhf(d / nrm);
    }
    ls[threadIdx.x] = sj;
    __syncthreads();
    if (i >= n) return;
    float si;
    {
        const float* xr = x + (size_t)i * 64;
        float d = 0.f;
        #pragma unroll
        for (int k = 0; k < 64; ++k) d += xr[k] * pl[k];
        si = tanhf(d / nrm);
    }
    const int j0 = blockIdx.y * 256;
    int jj_n = n - j0; if (jj_n > 256) jj_n = 256;
    int cnt = 0;
    for (int jj = 0; jj < jj_n; ++jj) {
        float s2 = ls[jj];
        cnt += (s2 > si) || (s2 == si && (j0 + jj) < i);
    }
    atomicAdd(&rank[i], cnt);
}

// fused: perm[rank]=i, scout (inline score), pooled rows
__global__ void k_topk_finish(const float* __restrict__ x, const float* __restrict__ pv,
                              const int* __restrict__ rank, int n, int k, int kp,
                              int* __restrict__ perm, float* __restrict__ scout,
                              float* __restrict__ xo) {
    __shared__ float pl[64];
    if (threadIdx.x < 64) pl[threadIdx.x] = pv[threadIdx.x];
    __syncthreads();
    float n2 = 0.f;
    #pragma unroll
    for (int kq = 0; kq < 64; ++kq) n2 += pl[kq] * pl[kq];
    const float nrm = sqrtf(n2);
    int i = blockIdx.x * blockDim.x + threadIdx.x;
    if (i < n) {
        int r = rank[i];
        if (r < k) {
            const float* xr = x + (size_t)i * 64;
            float d = 0.f;
            #pragma unroll
            for (int kq = 0; kq < 64; ++kq) d += xr[kq] * pl[kq];
            float s = tanhf(d / nrm);
            perm[r] = i; scout[r] = s;
            float* xw = xo + (size_t)r * 64;
            #pragma unroll 8
            for (int f = 0; f < 64; ++f) xw[f] = xr[f] * s;
        }
    }
    if (i >= k && i < kp) { perm[i] = 0; scout[i] = 0.f; }
}

// XW with optional fused unpool: in[i][k] = x[i][k] + (rank[i]<kpool ? xc[rank[i]][k] : 0)
// Y = dis*XW ; Yt = 3-way bf16 split of Y^T
__global__ void k_xw(const float* __restrict__ x, const float* __restrict__ W,
                     const float* __restrict__ dsum, const float* __restrict__ diag,
                     const float* __restrict__ xc, const int* __restrict__ rank, int kpool,
                     int n, int np, int cin, int ldw, int nout,
                     float* __restrict__ Y, unsigned short* __restrict__ T0,
                     unsigned short* __restrict__ T1, unsigned short* __restrict__ T2) {
    int t = blockIdx.x * blockDim.x + threadIdx.x;
    if (t >= np * 64) return;
    int i = t >> 6, f = t & 63;
    float y = 0.f;
    if (i < n && f < nout) {
        float a = 0.f;
        const float* xr = x + (size_t)i * cin;
        if (xc) {
            int r = rank[i];
            const float* cr = (r < kpool) ? (xc + (size_t)r * 64) : nullptr;
            if (cr) {
                for (int k = 0; k < cin; ++k) a += (xr[k] + cr[k]) * W[(size_t)k * ldw + f];
            } else {
                for (int k = 0; k < cin; ++k) a += xr[k] * W[(size_t)k * ldw + f];
            }
        } else {
            for (int k = 0; k < cin; ++k) a += xr[k] * W[(size_t)k * ldw + f];
        }
        y = disv(dsum, diag, i) * a;
    }
    Y[t] = y;
    unsigned short h0 = f2bf(y);
    float r1 = y - bf2f(h0);
    unsigned short h1 = f2bf(r1);
    float r2 = r1 - bf2f(h1);
    size_t ti = (size_t)f * np + i;
    T0[ti] = h0; T1[ti] = h1; T2[ti] = f2bf(r2);
}

// ---------------- MFMA GEMMs ----------------

// fp8 fused augment+pool (level 1): TM*32 tile; one b128/lane/row (both
// K-halves via the interleave), slot = kb ^ ((row>>1)&3).
template<int TM>
__global__ __launch_bounds__(256) void k_aug8(
    const unsigned char* __restrict__ P8, const unsigned char* __restrict__ Q8,
    const int* __restrict__ perm, int kk, int kp, int K, int ns,
    unsigned short* __restrict__ H0, unsigned short* __restrict__ T0,
    float* __restrict__ dsum)
{
    constexpr int BM = TM * 32;
    constexpr int PS = BM * 64;
    constexpr int D = 3;
    constexpr int STG = 2 * PS;
    constexpr int LPP = TM / 2;
    constexpr int LPS = 2 * LPP;
    constexpr int TRE = BM * (BM + 2) * 2;
    constexpr int SMEB = (D * STG > TRE) ? D * STG : TRE;
    __shared__ __align__(16) unsigned char smem[SMEB];
    const int tid = threadIdx.x, lane = tid & 63;
    const int wm = tid >> 7, wn = (tid >> 6) & 1;
    const int bm = blockIdx.x * BM, bn = blockIdx.y * BM;
    const unsigned char* spA[LPP];
    const unsigned char* spB[LPP];
    int dstb[LPP];
    #pragma unroll
    for (int it = 0; it < LPP; ++it) {
        int s = tid + it * 256;
        int row = s >> 2, c = (s & 3) ^ ((row >> 1) & 3);
        dstb[it] = (s - lane) * 16;
        spA[it] = P8 + (size_t)perm[bm + row] * ns + 16 * c;
        spB[it] = Q8 + (size_t)perm[bn + row] * ns + 16 * c;
    }
    f32x4 acc[TM][TM] = {};
    const int l15 = lane & 15, kb = lane >> 4;
    const int nt = K >> 6;

    auto stage = [&](int b, int koff) {
        unsigned char* base = smem + b * STG;
        #pragma unroll
        for (int it = 0; it < LPP; ++it) gload_lds16b(spA[it] + koff, base + dstb[it]);
        #pragma unroll
        for (int it = 0; it < LPP; ++it) gload_lds16b(spB[it] + koff, base + PS + dstb[it]);
    };
    auto compute = [&](int b) {
        const unsigned char* base = smem + b * STG;
        l64x2 av[TM], bv[TM];
        #pragma unroll
        for (int mi = 0; mi < TM; ++mi) {
            int row = wm * (TM * 16) + mi * 16 + l15;
            int slot = kb ^ ((row >> 1) & 3);
            av[mi] = *(const l64x2*)(base + row * 64 + slot * 16);
        }
        #pragma unroll
        for (int ni = 0; ni < TM; ++ni) {
            int row = wn * (TM * 16) + ni * 16 + l15;
            int slot = kb ^ ((row >> 1) & 3);
            bv[ni] = *(const l64x2*)(base + PS + row * 64 + slot * 16);
        }
        #pragma unroll
        for (int h = 0; h < 2; ++h)
            #pragma unroll
            for (int mi = 0; mi < TM; ++mi)
                #pragma unroll
                for (int ni = 0; ni < TM; ++ni)
                    acc[mi][ni] = __builtin_amdgcn_mfma_f32_16x16x32_fp8_fp8(
                        av[mi][h], bv[ni][h], acc[mi][ni], 0, 0, 0);
    };

    stage(0, 0); stage(1, 64);
    for (int t = 0; t < nt; ++t) {
        const int ahead = nt - 1 - t;
        if (ahead >= D - 1) {
            stage((t + D - 1) % D, (t + D - 1) * 64);
            waitvm<2 * LPS>();
        } else if (ahead == 1) {
            waitvm<LPS>();
        } else {
            waitvm<0>();
        }
        __builtin_amdgcn_sched_barrier(0);
        __builtin_amdgcn_s_barrier();
        compute(t % D);
        __builtin_amdgcn_s_barrier();
    }

    const int hi = lane >> 4;
    #pragma unroll
    for (int mi = 0; mi < TM; ++mi)
        #pragma unroll
        for (int r = 0; r < 4; ++r) {
            int row = bm + wm * (TM * 16) + mi * 16 + hi * 4 + r;
            float s = 0.f;
            #pragma unroll
            for (int ni = 0; ni < TM; ++ni) {
                int col = bn + wn * (TM * 16) + ni * 16 + l15;
                float v = (row < kk && col < kk) ? ((row == col) ? 1.f : acc[mi][ni][r]) : 0.f;
                H0[(size_t)row * kp + col] = f2bf(v);
                s += v;
            }
            #pragma unroll
            for (int m = 1; m < 16; m <<= 1) s += __shfl_xor(s, m);
            if (l15 == 0) atomicAdd(&dsum[row], s);
        }

    unsigned short* smw = (unsigned short*)smem;
    __syncthreads();
    #pragma unroll
    for (int mi = 0; mi < TM; ++mi)
        #pragma unroll
        for (int ni = 0; ni < TM; ++ni)
            #pragma unroll
            for (int r = 0; r < 4; ++r) {
                int rl = wm * (TM * 16) + mi * 16 + hi * 4 + r;
                int cl = wn * (TM * 16) + ni * 16 + l15;
                int row = bm + rl, col = bn + cl;
                float v = (row < kk && col < kk) ? ((row == col) ? 1.f : acc[mi][ni][r]) : 0.f;
                smw[rl * (BM + 2) + cl] = f2bf(v);
            }
    __syncthreads();
    #pragma unroll
    for (int e = 0; e < BM * BM / 256; ++e) {
        int idx = tid + e * 256;
        int j = idx / BM, i = idx & (BM - 1);
        T0[(size_t)(bn + j) * kp + (bm + i)] = smw[i * (BM + 2) + j];
    }
}

// bf16 fused augment+pool+split (levels 2-3)
template<int TM, int PA, int PB, int NP, int NT>
__global__ __launch_bounds__(256) void k_aug2(
    const unsigned short* __restrict__ Pa, const unsigned short* __restrict__ Pb,
    const unsigned short* __restrict__ Qa, const unsigned short* __restrict__ Qb,
    const int* __restrict__ perm, int kk, int kp, int K, int ns,
    unsigned short* __restrict__ H0, unsigned short* __restrict__ H1,
    unsigned short* __restrict__ H2,
    unsigned short* __restrict__ T0, unsigned short* __restrict__ T1,
    float* __restrict__ dsum)
{
    constexpr int BM  = TM * 32;
    constexpr int PS  = TM * 2048;
    constexpr int D   = 3;
    constexpr int STG = (PA + PB) * PS;
    constexpr int LPS = TM * (PA + PB);
    constexpr int TRE = NT ? (BM * (BM + 2)) : 0;
    constexpr int SME = (D * STG > TRE) ? (D * STG) : TRE;
    __shared__ __align__(16) unsigned short smem[SME];
    const int tid = threadIdx.x, lane = tid & 63;
    const int wm = tid >> 7, wn = (tid >> 6) & 1;
    const int bm = blockIdx.x * BM, bn = blockIdx.y * BM;
    const unsigned short* P[2] = {Pa, Pb};
    const unsigned short* Q[2] = {Qa, Qb};
    const unsigned short* sp[PA][TM];
    const unsigned short* sq[PB][TM];
    int dst[TM];
    #pragma unroll
    for (int it = 0; it < TM; ++it) {
        int s = tid + it * 256;
        int row = s >> 3, c = (s & 7) ^ (row & 7);
        dst[it] = (s - lane) * 8;
        #pragma unroll
        for (int p = 0; p < PA; ++p)
            sp[p][it] = P[p] + (size_t)perm[bm + row] * ns + 8 * c;
        #pragma unroll
        for (int p = 0; p < PB; ++p)
            sq[p][it] = Q[p] + (size_t)perm[bn + row] * ns + 8 * c;
    }
    f32x4 acc[TM][TM] = {};
    const int l15 = lane & 15, kb = lane >> 4;
    const int nt = K >> 6;

    auto stage = [&](int b, int koff) {
        unsigned short* base = smem + b * STG;
        #pragma unroll
        for (int p = 0; p < PA; ++p)
            #pragma unroll
            for (int it = 0; it < TM; ++it)
                gload_lds16(sp[p][it] + koff, base + p * PS + dst[it]);
        #pragma unroll
        for (int p = 0; p < PB; ++p)
            #pragma unroll
            for (int it = 0; it < TM; ++it)
                gload_lds16(sq[p][it] + koff, base + PA * PS + p * PS + dst[it]);
    };
    auto compute = [&](int b) {
        const unsigned short* base = smem + b * STG;
        #pragma unroll
        for (int h = 0; h < 2; ++h) {
            s16x8 av[PA][TM], bv[PB][TM];
            #pragma unroll
            for (int p = 0; p < PA; ++p)
                #pragma unroll
                for (int mi = 0; mi < TM; ++mi) {
                    int row = wm * (TM * 16) + mi * 16 + l15;
                    int slot = (h * 4 + kb) ^ (row & 7);
                    av[p][mi] = *(const s16x8*)(base + p * PS + row * 64 + slot * 8);
                }
            #pragma unroll
            for (int p = 0; p < PB; ++p)
                #pragma unroll
                for (int ni = 0; ni < TM; ++ni) {
                    int row = wn * (TM * 16) + ni * 16 + l15;
                    int slot = (h * 4 + kb) ^ (row & 7);
                    bv[p][ni] = *(const s16x8*)(base + PA * PS + p * PS + row * 64 + slot * 8);
                }
            #pragma unroll
            for (int mi = 0; mi < TM; ++mi)
                #pragma unroll
                for (int ni = 0; ni < TM; ++ni)
                    #pragma unroll
                    for (int pa = 0; pa < PA; ++pa)
                        #pragma unroll
                        for (int pb = 0; pb < PB; ++pb)
                            acc[mi][ni] = __builtin_amdgcn_mfma_f32_16x16x32_bf16(
                                av[pa][mi], bv[pb][ni], acc[mi][ni], 0, 0, 0);
        }
    };

    for (int i = 0; i < D - 1; ++i) stage(i, i * 64);
    for (int t = 0; t < nt; ++t) {
        const int ahead = nt - 1 - t;
        if (ahead >= D - 1) {
            stage((t + D - 1) % D, (t + D - 1) * 64);
            waitvm<2 * LPS>();
        } else if (ahead == 1) {
            waitvm<LPS>();
        } else {
            waitvm<0>();
        }
        __builtin_amdgcn_sched_barrier(0);
        __builtin_amdgcn_s_barrier();
        compute(t % D);
        __builtin_amdgcn_s_barrier();
    }

    const int hi = lane >> 4;
    #pragma unroll
    for (int mi = 0; mi < TM; ++mi)
        #pragma unroll
        for (int r = 0; r < 4; ++r) {
            int row = bm + wm * (TM * 16) + mi * 16 + hi * 4 + r;
            float s = 0.f;
            #pragma unroll
            for (int ni = 0; ni < TM; ++ni) {
                int col = bn + wn * (TM * 16) + ni * 16 + l15;
                float v = (row < kk && col < kk) ? ((row == col) ? 1.f : acc[mi][ni][r]) : 0.f;
                s += v;
                unsigned short h0 = f2bf(v);
                size_t o = (size_t)row * kp + col;
                H0[o] = h0;
                if (NP > 1) {
                    float r1 = v - bf2f(h0);
                    unsigned short h1 = f2bf(r1);
                    H1[o] = h1;
                    if (NP > 2) H2[o] = f2bf(r1 - bf2f(h1));
                }
            }
            #pragma unroll
            for (int m = 1; m < 16; m <<= 1) s += __shfl_xor(s, m);
            if (l15 == 0) atomicAdd(&dsum[row], s);
        }

    if (NT > 0) {
        #pragma unroll
        for (int pass = 0; pass < NT; ++pass) {
            __syncthreads();
            #pragma unroll
            for (int mi = 0; mi < TM; ++mi)
                #pragma unroll
                for (int ni = 0; ni < TM; ++ni)
                    #pragma unroll
                    for (int r = 0; r < 4; ++r) {
                        int rl = wm * (TM * 16) + mi * 16 + hi * 4 + r;
                        int cl = wn * (TM * 16) + ni * 16 + l15;
                        int row = bm + rl, col = bn + cl;
                        float v = (row < kk && col < kk) ? ((row == col) ? 1.f : acc[mi][ni][r]) : 0.f;
                        unsigned short h0 = f2bf(v);
                        unsigned short hv = h0;
                        if (pass == 1) hv = f2bf(v - bf2f(h0));
                        smem[rl * (BM + 2) + cl] = hv;
                    }
            __syncthreads();
            unsigned short* T = pass ? T1 : T0;
            #pragma unroll
            for (int e = 0; e < BM * BM / 256; ++e) {
                int idx = tid + e * 256;
                int j = idx / BM, i = idx & (BM - 1);
                T[(size_t)(bn + j) * kp + (bm + i)] = smem[i * (BM + 2) + j];
            }
        }
    }
}

template<int PA>
__global__ __launch_bounds__(256) void k_gcn_gemm(
    const unsigned short* __restrict__ Aa, const unsigned short* __restrict__ Ab,
    const unsigned short* __restrict__ Ac,
    const unsigned short* __restrict__ B0, const unsigned short* __restrict__ B1,
    const unsigned short* __restrict__ B2,
    int np, int kchunk, float* __restrict__ Zp)
{
    __shared__ __align__(16) unsigned short la[PA * 4096];
    __shared__ __align__(16) unsigned short lb[3 * 4096];
    const int tid = threadIdx.x, lane = tid & 63, wv = tid >> 6;
    const int bm = blockIdx.x * 64;
    const int kbeg = blockIdx.y * kchunk;
    const unsigned short* A[3] = {Aa, Ab, Ac};
    const unsigned short* B[3] = {B0, B1, B2};
    const unsigned short* sa[PA][2];
    const unsigned short* sb[3][2];
    int dst[2];
    #pragma unroll
    for (int it = 0; it < 2; ++it) {
        int s = tid + it * 256;
        int row = s >> 3, c = (s & 7) ^ (row & 7);
        dst[it] = (s - lane) * 8;
        #pragma unroll
        for (int p = 0; p < PA; ++p)
            sa[p][it] = A[p] + (size_t)(bm + row) * np + kbeg + 8 * c;
        #pragma unroll
        for (int p = 0; p < 3; ++p)
            sb[p][it] = B[p] + (size_t)row * np + kbeg + 8 * c;
    }
    f32x4 acc[4] = {};
    const int l15 = lane & 15, kb = lane >> 4;
    const int nt = kchunk >> 6;

    for (int tt = 0; tt < nt; ++tt) {
        if (tt) __syncthreads();
        int koff = tt * 64;
        #pragma unroll
        for (int p = 0; p < PA; ++p)
            #pragma unroll
            for (int it = 0; it < 2; ++it)
                gload_lds16(sa[p][it] + koff, &la[p * 4096 + dst[it]]);
        #pragma unroll
        for (int p = 0; p < 3; ++p)
            #pragma unroll
            for (int it = 0; it < 2; ++it)
                gload_lds16(sb[p][it] + koff, &lb[p * 4096 + dst[it]]);
        __syncthreads();
        #pragma unroll
        for (int h = 0; h < 2; ++h) {
            s16x8 av[PA], bv[3][4];
            #pragma unroll
            for (int p = 0; p < PA; ++p) {
                int row = wv * 16 + l15;
                int slot = (h * 4 + kb) ^ (row & 7);
                av[p] = *(const s16x8*)&la[p * 4096 + row * 64 + slot * 8];
            }
            #pragma unroll
            for (int p = 0; p < 3; ++p)
                #pragma unroll
                for (int ni = 0; ni < 4; ++ni) {
                    int row = ni * 16 + l15;
                    int slot = (h * 4 + kb) ^ (row & 7);
                    bv[p][ni] = *(const s16x8*)&lb[p * 4096 + row * 64 + slot * 8];
                }
            #pragma unroll
            for (int ni = 0; ni < 4; ++ni)
                #pragma unroll
                for (int pa = 0; pa < PA; ++pa)
                    #pragma unroll
                    for (int pb = 0; pb <= 2 - pa; ++pb)
                        acc[ni] = __builtin_amdgcn_mfma_f32_16x16x32_bf16(
                            av[pa], bv[pb][ni], acc[ni], 0, 0, 0);
        }
    }

    const int l4 = lane >> 4;
    float* Z = Zp + (size_t)blockIdx.y * np * 64;
    for (int ni = 0; ni < 4; ++ni)
        #pragma unroll
        for (int r = 0; r < 4; ++r) {
            int row = bm + wv * 16 + l4 * 4 + r;
            Z[(size_t)row * 64 + ni * 16 + l15] = acc[ni][r];
        }
}

// out = relu?( dis_i * (sum Z + (diag+1)*Y_i) + b ), dis inline
__global__ void k_gcn_epi(const float* __restrict__ Zp, const float* __restrict__ Y,
                          const float* __restrict__ dsum, const float* __restrict__ diagv,
                          const float* __restrict__ b, int n, int np, int nout, int relu,
                          int S, float* __restrict__ xo) {
    int t = blockIdx.x * blockDim.x + threadIdx.x;
    if (t >= n * 64) return;
    int i = t >> 6, f = t & 63;
    float s = 0.f;
    for (int kq = 0; kq < S; ++kq) s += Zp[(size_t)kq * np * 64 + t];
    float coef = 1.f + (diagv ? diagv[i] : 0.f);
    float v = disv(dsum, diagv, i) * (s + coef * Y[t]) + (f < nout ? b[f] : 0.f);
    if (relu) v = fmaxf(v, 0.f);
    xo[t] = v;
}

// final epilogue: logits (nout=3, no relu) + row softmax, one thread per row
__global__ void k_gcn_epi_sm(const float* __restrict__ Zp, const float* __restrict__ Y,
                             const float* __restrict__ dsum, const float* __restrict__ diagv,
                             const float* __restrict__ b, int n, int np, int S,
                             float* __restrict__ out) {
    int i = blockIdx.x * blockDim.x + threadIdx.x;
    if (i >= n) return;
    float dis = disv(dsum, diagv, i);
    float coef = 1.f + (diagv ? diagv[i] : 0.f);
    float v[3];
    #pragma unroll
    for (int f = 0; f < 3; ++f) {
        int t = i * 64 + f;
        float s = 0.f;
        for (int kq = 0; kq < S; ++kq) s += Zp[(size_t)kq * np * 64 + t];
        v[f] = dis * (s + coef * Y[t]) + b[f];
    }
    float m = fmaxf(v[0], fmaxf(v[1], v[2]));
    float e0 = expf(v[0] - m), e1 = expf(v[1] - m), e2 = expf(v[2] - m);
    float sum = e0 + e1 + e2;
    out[i * 3] = e0 / sum; out[i * 3 + 1] = e1 / sum; out[i * 3 + 2] = e2 / sum;
}

// ---------------- launch ----------------

extern "C" void kernel_launch(void* const* d_in, const int* in_sizes, int n_in,
                              void* d_out, int out_size, void* d_ws, size_t ws_size,
                              hipStream_t stream) {
    const int N0 = 3072;
    const int E = in_sizes[1] / 2;
    const int CIN = in_sizes[0] / N0;

    const float* x_in = (const float*)d_in[0];
    const int*   eidx = (const int*)d_in[1];
    const float* Wd0 = (const float*)d_in[2];  const float* bd0 = (const float*)d_in[3];
    const float* Wd1 = (const float*)d_in[4];  const float* bd1 = (const float*)d_in[5];
    const float* Wd2 = (const float*)d_in[6];  const float* bd2 = (const float*)d_in[7];
    const float* Wd3 = (const float*)d_in[8];  const float* bd3 = (const float*)d_in[9];
    const float* p1  = (const float*)d_in[10]; const float* p2  = (const float*)d_in[11];
    const float* p3  = (const float*)d_in[12];
    const float* Wu0 = (const float*)d_in[13]; const float* bu0 = (const float*)d_in[14];
    const float* Wu1 = (const float*)d_in[15]; const float* bu1 = (const float*)d_in[16];
    const float* Wu2 = (const float*)d_in[17]; const float* bu2 = (const float*)d_in[18];
    float* out = (float*)d_out;

    char* ws = (char*)d_ws;
    size_t off = 0;
    auto alloc = [&](size_t bytes) -> void* {
        off = (off + 255) & ~(size_t)255;
        void* p = ws + off;
        off += bytes;
        return p;
    };

    unsigned short* A0H  = (unsigned short*)alloc((size_t)3072 * 3072 * 2);
    unsigned char*  A0F8 = (unsigned char*)alloc((size_t)3072 * 3072);
    unsigned char*  A0T8 = (unsigned char*)alloc((size_t)3072 * 3072);
    float* d0   = (float*)alloc(3072 * 4);
    float* x0   = (float*)alloc((size_t)3072 * 64 * 4);
    unsigned short* P1H = (unsigned short*)alloc((size_t)2048 * 2048 * 2);
    unsigned short* P1T = (unsigned short*)alloc((size_t)2048 * 2048 * 2);
    float* x1   = (float*)alloc((size_t)2048 * 64 * 4);
    float* xp1  = (float*)alloc((size_t)2048 * 64 * 4);
    unsigned short* P2H  = (unsigned short*)alloc((size_t)1024 * 1024 * 2);
    unsigned short* P2L  = (unsigned short*)alloc((size_t)1024 * 1024 * 2);
    unsigned short* P2TH = (unsigned short*)alloc((size_t)1024 * 1024 * 2);
    unsigned short* P2TL = (unsigned short*)alloc((size_t)1024 * 1024 * 2);
    float* x2   = (float*)alloc((size_t)1024 * 64 * 4);
    float* xp2  = (float*)alloc((size_t)1024 * 64 * 4);
    unsigned short* P3a = (unsigned short*)alloc((size_t)512 * 512 * 2);
    unsigned short* P3b = (unsigned short*)alloc((size_t)512 * 512 * 2);
    unsigned short* P3c = (unsigned short*)alloc((size_t)512 * 512 * 2);
    float* x3   = (float*)alloc((size_t)512 * 64 * 4);
    float* xp3  = (float*)alloc((size_t)512 * 64 * 4);
    int*   perm1 = (int*)alloc(2048 * 4);  float* sc1 = (float*)alloc(2048 * 4);
    int*   perm2 = (int*)alloc(1024 * 4);  float* sc2 = (float*)alloc(1024 * 4);
    int*   perm3 = (int*)alloc(512 * 4);   float* sc3 = (float*)alloc(512 * 4);
    float* Yf  = (float*)alloc((size_t)3072 * 64 * 4);
    unsigned short* Yt0 = (unsigned short*)alloc((size_t)64 * 3072 * 2);
    unsigned short* Yt1 = (unsigned short*)alloc((size_t)64 * 3072 * 2);
    unsigned short* Yt2 = (unsigned short*)alloc((size_t)64 * 3072 * 2);
    float* Zp   = (float*)alloc((size_t)16 * 3072 * 64 * 4);
    // zeroed-each-launch region: dsum0..3 + rank1..3 + A0f contiguous (ONE memset)
    float* dsum0 = (float*)alloc(3072 * 4);
    float* dsum1 = (float*)alloc(2048 * 4);
    float* dsum2 = (float*)alloc(1024 * 4);
    float* dsum3 = (float*)alloc(512 * 4);
    int* rank1 = (int*)alloc(3072 * 4);
    int* rank2 = (int*)alloc(2048 * 4);
    int* rank3 = (int*)alloc(1024 * 4);
    char* scratch = (char*)alloc((size_t)3072 * 3072 * 4);
    if (off > ws_size) return;

    float* A0f = (float*)scratch;

    auto gcn = [&](const float* xin, int cin, const float* W, int ldw, int nout, const float* bias,
                   const unsigned short* Pa, const unsigned short* Pb2, const unsigned short* Pc,
                   int PA, int n, int np2, const float* dsum, const float* diagv,
                   const float* xc, const int* rank, int kpool, int relu, float* xout) {
        k_xw<<<DIVUP(np2 * 64, 256), 256, 0, stream>>>(xin, W, dsum, diagv, xc, rank, kpool,
                                                       n, np2, cin, ldw, nout, Yf, Yt0, Yt1, Yt2);
        int S = (np2 == 1024) ? 16 : 8;
        int kch = np2 / S;
        dim3 gg(np2 / 64, S);
        if (PA == 1)      k_gcn_gemm<1><<<gg, 256, 0, stream>>>(Pa, Pa, Pa, Yt0, Yt1, Yt2, np2, kch, Zp);
        else if (PA == 2) k_gcn_gemm<2><<<gg, 256, 0, stream>>>(Pa, Pb2, Pb2, Yt0, Yt1, Yt2, np2, kch, Zp);
        else              k_gcn_gemm<3><<<gg, 256, 0, stream>>>(Pa, Pb2, Pc, Yt0, Yt1, Yt2, np2, kch, Zp);
        if (xout)
            k_gcn_epi<<<DIVUP(n * 64, 256), 256, 0, stream>>>(Zp, Yf, dsum, diagv, bias, n, np2, nout, relu, S, xout);
        else
            k_gcn_epi_sm<<<DIVUP(n, 256), 256, 0, stream>>>(Zp, Yf, dsum, diagv, bias, n, np2, S, out);
    };

    auto topk = [&](const float* x, const float* pvec, int n, int k, int kp,
                    int* rank, int* perm, float* scv, float* xo) {
        dim3 gr(DIVUP(n, 256), DIVUP(n, 256));
        k_count_rank<<<gr, 256, 0, stream>>>(x, pvec, rank, n);
        k_topk_finish<<<DIVUP(n, 256), 256, 0, stream>>>(x, pvec, rank, n, k, kp, perm, scv, xo);
    };

    // one memset: dsum0..rank3 + A0f (all zero-init, contiguous)
    hipMemsetAsync(dsum0, 0, ((char*)A0f + (size_t)3072 * 3072 * 4) - (char*)dsum0, stream);

    k_scatter<<<DIVUP(E, 256), 256, 0, stream>>>(eidx, A0f, E, N0);
    k_a0_plane<<<3072 * 3072 / 256, 256, 0, stream>>>(A0f, A0H, A0F8, d0, dsum0, N0);
    k_transpose_i8<<<dim3(48, 48), 256, 0, stream>>>(A0F8, A0T8, 3072);

    gcn(x_in, CIN, Wd0, 64, 64, bd0, A0H, A0H, A0H, 1, 3072, 3072, dsum0, d0,
        nullptr, nullptr, 0, 1, x0);

    topk(x0, p1, 3072, 2000, 2048, rank1, perm1, sc1, xp1);
    k_aug8<2><<<dim3(32, 32), 256, 0, stream>>>(
        A0F8, A0T8, perm1, 2000, 2048, 3072, 3072, P1H, P1T, dsum1);
    gcn(xp1, 64, Wd1, 64, 64, bd1, P1H, P1H, P1H, 1, 2000, 2048, dsum1, nullptr,
        nullptr, nullptr, 0, 1, x1);

    topk(x1, p2, 2000, 1000, 1024, rank2, perm2, sc2, xp2);
    k_aug2<2, 1, 1, 2, 2><<<dim3(16, 16), 256, 0, stream>>>(
        P1H, P1H, P1T, P1T, perm2, 1000, 1024, 2048, 2048, P2H, P2L, P2L, P2TH, P2TL, dsum2);
    gcn(xp2, 64, Wd2, 64, 64, bd2, P2H, P2L, P2L, 2, 1000, 1024, dsum2, nullptr,
        nullptr, nullptr, 0, 1, x2);

    topk(x2, p3, 1000, 500, 512, rank3, perm3, sc3, xp3);
    k_aug2<2, 2, 2, 3, 0><<<dim3(8, 8), 256, 0, stream>>>(
        P2H, P2L, P2TH, P2TL, perm3, 500, 512, 1024, 1024, P3a, P3b, P3c, nullptr, nullptr, dsum3);
    gcn(xp3, 64, Wd3, 64, 64, bd3, P3a, P3b, P3c, 3, 500, 512, dsum3, nullptr,
        nullptr, nullptr, 0, 1, x3);

    // up 0: res=x2 + unpool(x3 via rank3)
    gcn(x2, 64, Wu0, 64, 64, bu0, P2H, P2L, P2L, 2, 1000, 1024, dsum2, nullptr,
        x3, rank3, 500, 1, xp2);

    // up 1: res=x1 + unpool(xp2 via rank2)
    gcn(x1, 64, Wu1, 64, 64, bu1, P1H, P1H, P1H, 1, 2000, 2048, dsum1, nullptr,
        xp2, rank2, 1000, 1, xp1);

    // up 2: res=x0 + unpool(xp1 via rank1), logits+softmax fused
    gcn(x0, 64, Wu2, 3, 3, bu2, A0H, A0H, A0H, 1, 3072, 3072, dsum0, d0,
        xp1, rank1, 2000, 0, nullptr);
}

// Round 14
// 384.069 us; speedup vs baseline: 1.0392x; 1.0015x over previous
//
#include <hip/hip_runtime.h>
#include <hip/hip_bf16.h>
#include <cstdint>
#include <cstddef>
#include <math.h>

// GraphUNet forward on MI355X.
// Level-1 augment in fp8 e4m3 (integer entries: exact), K-interleaved rows
// for conflict-free b128 LDS reads, 64^2 tiles, K-step 128 pipeline;
// deeper levels bf16 splits. Fused augment+pool writes planes + transposes
// + row sums. Rank-based top-k with inline scores; unpool fused into xw;
// softmax fused into the final epilogue. global_load_lds staging,
// counted-vmcnt pipelines.

#define DIVUP(a,b) (((a)+(b)-1)/(b))

using s16x8 = __attribute__((ext_vector_type(8))) short;
using f32x4 = __attribute__((ext_vector_type(4))) float;
using l64x2 = __attribute__((ext_vector_type(2))) long;

template<int N> __device__ __forceinline__ void waitvm() {
    if constexpr (N == 0)       asm volatile("s_waitcnt vmcnt(0)" ::: "memory");
    else if constexpr (N == 2)  asm volatile("s_waitcnt vmcnt(2)" ::: "memory");
    else if constexpr (N == 4)  asm volatile("s_waitcnt vmcnt(4)" ::: "memory");
    else if constexpr (N == 8)  asm volatile("s_waitcnt vmcnt(8)" ::: "memory");
    else                        asm volatile("s_waitcnt vmcnt(16)" ::: "memory");
}

__device__ __forceinline__ unsigned short f2bf(float v) {
    union { float f; unsigned u; } a; a.f = v;
    unsigned u = a.u;
    u = u + 0x7FFFu + ((u >> 16) & 1u);   // RNE
    return (unsigned short)(u >> 16);
}
__device__ __forceinline__ float bf2f(unsigned short h) {
    union { unsigned u; float f; } a; a.u = ((unsigned)h) << 16; return a.f;
}
__device__ __forceinline__ unsigned char f2e4m3(float v) {
    if (v <= 0.f) return 0;
    int e = 0; float m = v;
    while (m >= 2.f) { m *= 0.5f; ++e; }
    int mant = (int)(m * 8.f + 0.5f) - 8;
    if (mant >= 8) { mant = 0; ++e; }
    return (unsigned char)(((e + 7) << 3) | mant);
}
// K-interleave within 64-elem row: x = h*32 + kb*8 + e  ->  kb*16 + h*8 + e
__device__ __forceinline__ int perm64(int x) {
    return ((x >> 3) & 3) * 16 + ((x >> 5) & 1) * 8 + (x & 7);
}
__device__ __forceinline__ float disv(const float* dsum, const float* diag, int i) {
    float deg = dsum[i] + 1.0f + (diag ? diag[i] : 0.0f);
    return deg > 0.f ? 1.0f / sqrtf(deg) : 0.f;
}
__device__ __forceinline__ void gload_lds16(const unsigned short* g, unsigned short* l) {
    __builtin_amdgcn_global_load_lds(
        (const __attribute__((address_space(1))) void*)g,
        (__attribute__((address_space(3))) void*)l, 16, 0, 0);
}
__device__ __forceinline__ void gload_lds16b(const unsigned char* g, unsigned char* l) {
    __builtin_amdgcn_global_load_lds(
        (const __attribute__((address_space(1))) void*)g,
        (__attribute__((address_space(3))) void*)l, 16, 0, 0);
}

// ---------------- small kernels ----------------

__global__ void k_scatter(const int* __restrict__ e, float* __restrict__ A, int E, int n) {
    int t = blockIdx.x * blockDim.x + threadIdx.x;
    if (t < E) atomicAdd(&A[(size_t)e[t] * n + e[E + t]], 1.0f);
}

// plane (diag->1): bf16 + interleaved fp8 + fused row-sum
__global__ void k_a0_plane(const float* __restrict__ A, unsigned short* __restrict__ H,
                           unsigned char* __restrict__ F8,
                           float* __restrict__ d0, float* __restrict__ dsum, int n) {
    int t = blockIdx.x * 256 + threadIdx.x;
    int i = t / n, j = t - i * n;
    float v = A[t];
    if (i == j) { d0[i] = v; v = 1.0f; }
    H[t] = f2bf(v);
    F8[(size_t)i * n + (j & ~63) + perm64(j & 63)] = f2e4m3(v);
    __shared__ float red[256];
    red[threadIdx.x] = v; __syncthreads();
    for (int o = 128; o > 0; o >>= 1) {
        if (threadIdx.x < o) red[threadIdx.x] += red[threadIdx.x + o];
        __syncthreads();
    }
    if (threadIdx.x == 0) atomicAdd(&dsum[i], red[0]);
}

// interleaved-fp8 transpose: D[c][interleaved r] = A[r][c] (64x64 tiles)
__global__ void k_transpose_i8(const unsigned char* __restrict__ S, unsigned char* __restrict__ D, int n) {
    __shared__ unsigned char tile[64][65];
    int bx = blockIdx.x * 64, by = blockIdx.y * 64;
    const int tx = threadIdx.x & 63, ty = threadIdx.x >> 6;
    #pragma unroll
    for (int dy = 0; dy < 64; dy += 4)
        tile[ty + dy][tx] = S[(size_t)(by + ty + dy) * n + bx + perm64(tx)];
    __syncthreads();
    #pragma unroll
    for (int dy = 0; dy < 64; dy += 4)
        D[(size_t)(bx + ty + dy) * n + by + perm64(tx)] = tile[tx][ty + dy];
}

// stable rank under (score desc, idx asc) with INLINE scores (== jax.lax.top_k)
__global__ void k_count_rank(const float* __restrict__ x, const float* __restrict__ pv,
                             int* __restrict__ rank, int n) {
    __shared__ float pl[64];
    __shared__ float ls[256];
    if (threadIdx.x < 64) pl[threadIdx.x] = pv[threadIdx.x];
    __syncthreads();
    float n2 = 0.f;
    #pragma unroll
    for (int k = 0; k < 64; ++k) n2 += pl[k] * pl[k];
    const float nrm = sqrtf(n2);
    const int i = blockIdx.x * 256 + threadIdx.x;
    const int j = blockIdx.y * 256 + threadIdx.x;
    float sj = -INFINITY;
    if (j < n) {
        const float* xr = x + (size_t)j * 64;
        float d = 0.f;
        #pragma unroll
        for (int k = 0; k < 64; ++k) d += xr[k] * pl[k];
        sj = tanhf(d / nrm);
    }
    ls[threadIdx.x] = sj;
    __syncthreads();
    if (i >= n) return;
    float si;
    {
        const float* xr = x + (size_t)i * 64;
        float d = 0.f;
        #pragma unroll
        for (int k = 0; k < 64; ++k) d += xr[k] * pl[k];
        si = tanhf(d / nrm);
    }
    const int j0 = blockIdx.y * 256;
    int jj_n = n - j0; if (jj_n > 256) jj_n = 256;
    int cnt = 0;
    for (int jj = 0; jj < jj_n; ++jj) {
        float s2 = ls[jj];
        cnt += (s2 > si) || (s2 == si && (j0 + jj) < i);
    }
    atomicAdd(&rank[i], cnt);
}

// fused: perm[rank]=i, scout (inline score), pooled rows
__global__ void k_topk_finish(const float* __restrict__ x, const float* __restrict__ pv,
                              const int* __restrict__ rank, int n, int k, int kp,
                              int* __restrict__ perm, float* __restrict__ scout,
                              float* __restrict__ xo) {
    __shared__ float pl[64];
    if (threadIdx.x < 64) pl[threadIdx.x] = pv[threadIdx.x];
    __syncthreads();
    float n2 = 0.f;
    #pragma unroll
    for (int kq = 0; kq < 64; ++kq) n2 += pl[kq] * pl[kq];
    const float nrm = sqrtf(n2);
    int i = blockIdx.x * blockDim.x + threadIdx.x;
    if (i < n) {
        int r = rank[i];
        if (r < k) {
            const float* xr = x + (size_t)i * 64;
            float d = 0.f;
            #pragma unroll
            for (int kq = 0; kq < 64; ++kq) d += xr[kq] * pl[kq];
            float s = tanhf(d / nrm);
            perm[r] = i; scout[r] = s;
            float* xw = xo + (size_t)r * 64;
            #pragma unroll 8
            for (int f = 0; f < 64; ++f) xw[f] = xr[f] * s;
        }
    }
    if (i >= k && i < kp) { perm[i] = 0; scout[i] = 0.f; }
}

// XW with optional fused unpool: in[i][k] = x[i][k] + (rank[i]<kpool ? xc[rank[i]][k] : 0)
// Y = dis*XW ; Yt = 3-way bf16 split of Y^T
__global__ void k_xw(const float* __restrict__ x, const float* __restrict__ W,
                     const float* __restrict__ dsum, const float* __restrict__ diag,
                     const float* __restrict__ xc, const int* __restrict__ rank, int kpool,
                     int n, int np, int cin, int ldw, int nout,
                     float* __restrict__ Y, unsigned short* __restrict__ T0,
                     unsigned short* __restrict__ T1, unsigned short* __restrict__ T2) {
    int t = blockIdx.x * blockDim.x + threadIdx.x;
    if (t >= np * 64) return;
    int i = t >> 6, f = t & 63;
    float y = 0.f;
    if (i < n && f < nout) {
        float a = 0.f;
        const float* xr = x + (size_t)i * cin;
        if (xc) {
            int r = rank[i];
            const float* cr = (r < kpool) ? (xc + (size_t)r * 64) : nullptr;
            if (cr) {
                for (int k = 0; k < cin; ++k) a += (xr[k] + cr[k]) * W[(size_t)k * ldw + f];
            } else {
                for (int k = 0; k < cin; ++k) a += xr[k] * W[(size_t)k * ldw + f];
            }
        } else {
            for (int k = 0; k < cin; ++k) a += xr[k] * W[(size_t)k * ldw + f];
        }
        y = disv(dsum, diag, i) * a;
    }
    Y[t] = y;
    unsigned short h0 = f2bf(y);
    float r1 = y - bf2f(h0);
    unsigned short h1 = f2bf(r1);
    float r2 = r1 - bf2f(h1);
    size_t ti = (size_t)f * np + i;
    T0[ti] = h0; T1[ti] = h1; T2[ti] = f2bf(r2);
}

// ---------------- MFMA GEMMs ----------------

// fp8 fused augment+pool (level 1): TM*32 tile; K-step 128 per pipeline slot
// (two 64-col chunks per buffer). One b128/lane/row/chunk (both K-halves via
// the interleave), slot = kb ^ ((row>>1)&3).
template<int TM>
__global__ __launch_bounds__(256) void k_aug8(
    const unsigned char* __restrict__ P8, const unsigned char* __restrict__ Q8,
    const int* __restrict__ perm, int kk, int kp, int K, int ns,
    unsigned short* __restrict__ H0, unsigned short* __restrict__ T0,
    float* __restrict__ dsum)
{
    constexpr int BM = TM * 32;
    constexpr int PS = BM * 64;                // bytes per plane per 64-chunk
    constexpr int CH = 2 * PS;                 // A+B per 64-chunk
    constexpr int D = 3;
    constexpr int STG = 2 * CH;                // two chunks (128 K-cols) per buffer
    constexpr int LPP = TM / 2;                // 16B loads per plane per thread per chunk
    constexpr int LPS = 4 * LPP;               // loads/thread/stage (2 chunks x 2 planes)
    constexpr int TRE = BM * (BM + 2) * 2;
    constexpr int SMEB = (D * STG > TRE) ? D * STG : TRE;
    __shared__ __align__(16) unsigned char smem[SMEB];
    const int tid = threadIdx.x, lane = tid & 63;
    const int wm = tid >> 7, wn = (tid >> 6) & 1;
    const int bm = blockIdx.x * BM, bn = blockIdx.y * BM;
    const unsigned char* spA[LPP];
    const unsigned char* spB[LPP];
    int dstb[LPP];
    #pragma unroll
    for (int it = 0; it < LPP; ++it) {
        int s = tid + it * 256;
        int row = s >> 2, c = (s & 3) ^ ((row >> 1) & 3);
        dstb[it] = (s - lane) * 16;
        spA[it] = P8 + (size_t)perm[bm + row] * ns + 16 * c;
        spB[it] = Q8 + (size_t)perm[bn + row] * ns + 16 * c;
    }
    f32x4 acc[TM][TM] = {};
    const int l15 = lane & 15, kb = lane >> 4;
    const int nt = K >> 7;                     // 128 K-cols per iteration

    auto stage = [&](int b, int koff) {
        #pragma unroll
        for (int c = 0; c < 2; ++c) {
            unsigned char* base = smem + b * STG + c * CH;
            #pragma unroll
            for (int it = 0; it < LPP; ++it) gload_lds16b(spA[it] + koff + c * 64, base + dstb[it]);
            #pragma unroll
            for (int it = 0; it < LPP; ++it) gload_lds16b(spB[it] + koff + c * 64, base + PS + dstb[it]);
        }
    };
    auto compute = [&](int b) {
        #pragma unroll
        for (int c = 0; c < 2; ++c) {
            const unsigned char* base = smem + b * STG + c * CH;
            l64x2 av[TM], bv[TM];
            #pragma unroll
            for (int mi = 0; mi < TM; ++mi) {
                int row = wm * (TM * 16) + mi * 16 + l15;
                int slot = kb ^ ((row >> 1) & 3);
                av[mi] = *(const l64x2*)(base + row * 64 + slot * 16);
            }
            #pragma unroll
            for (int ni = 0; ni < TM; ++ni) {
                int row = wn * (TM * 16) + ni * 16 + l15;
                int slot = kb ^ ((row >> 1) & 3);
                bv[ni] = *(const l64x2*)(base + PS + row * 64 + slot * 16);
            }
            #pragma unroll
            for (int h = 0; h < 2; ++h)
                #pragma unroll
                for (int mi = 0; mi < TM; ++mi)
                    #pragma unroll
                    for (int ni = 0; ni < TM; ++ni)
                        acc[mi][ni] = __builtin_amdgcn_mfma_f32_16x16x32_fp8_fp8(
                            av[mi][h], bv[ni][h], acc[mi][ni], 0, 0, 0);
        }
    };

    stage(0, 0); stage(1, 128);
    for (int t = 0; t < nt; ++t) {
        const int ahead = nt - 1 - t;
        if (ahead >= D - 1) {
            stage((t + D - 1) % D, (t + D - 1) * 128);
            waitvm<2 * LPS>();
        } else if (ahead == 1) {
            waitvm<LPS>();
        } else {
            waitvm<0>();
        }
        __builtin_amdgcn_sched_barrier(0);
        __builtin_amdgcn_s_barrier();
        compute(t % D);
        __builtin_amdgcn_s_barrier();
    }

    const int hi = lane >> 4;
    #pragma unroll
    for (int mi = 0; mi < TM; ++mi)
        #pragma unroll
        for (int r = 0; r < 4; ++r) {
            int row = bm + wm * (TM * 16) + mi * 16 + hi * 4 + r;
            float s = 0.f;
            #pragma unroll
            for (int ni = 0; ni < TM; ++ni) {
                int col = bn + wn * (TM * 16) + ni * 16 + l15;
                float v = (row < kk && col < kk) ? ((row == col) ? 1.f : acc[mi][ni][r]) : 0.f;
                H0[(size_t)row * kp + col] = f2bf(v);
                s += v;
            }
            #pragma unroll
            for (int m = 1; m < 16; m <<= 1) s += __shfl_xor(s, m);
            if (l15 == 0) atomicAdd(&dsum[row], s);
        }

    unsigned short* smw = (unsigned short*)smem;
    __syncthreads();
    #pragma unroll
    for (int mi = 0; mi < TM; ++mi)
        #pragma unroll
        for (int ni = 0; ni < TM; ++ni)
            #pragma unroll
            for (int r = 0; r < 4; ++r) {
                int rl = wm * (TM * 16) + mi * 16 + hi * 4 + r;
                int cl = wn * (TM * 16) + ni * 16 + l15;
                int row = bm + rl, col = bn + cl;
                float v = (row < kk && col < kk) ? ((row == col) ? 1.f : acc[mi][ni][r]) : 0.f;
                smw[rl * (BM + 2) + cl] = f2bf(v);
            }
    __syncthreads();
    #pragma unroll
    for (int e = 0; e < BM * BM / 256; ++e) {
        int idx = tid + e * 256;
        int j = idx / BM, i = idx & (BM - 1);
        T0[(size_t)(bn + j) * kp + (bm + i)] = smw[i * (BM + 2) + j];
    }
}

// bf16 fused augment+pool+split (levels 2-3)
template<int TM, int PA, int PB, int NP, int NT>
__global__ __launch_bounds__(256) void k_aug2(
    const unsigned short* __restrict__ Pa, const unsigned short* __restrict__ Pb,
    const unsigned short* __restrict__ Qa, const unsigned short* __restrict__ Qb,
    const int* __restrict__ perm, int kk, int kp, int K, int ns,
    unsigned short* __restrict__ H0, unsigned short* __restrict__ H1,
    unsigned short* __restrict__ H2,
    unsigned short* __restrict__ T0, unsigned short* __restrict__ T1,
    float* __restrict__ dsum)
{
    constexpr int BM  = TM * 32;
    constexpr int PS  = TM * 2048;
    constexpr int D   = 3;
    constexpr int STG = (PA + PB) * PS;
    constexpr int LPS = TM * (PA + PB);
    constexpr int TRE = NT ? (BM * (BM + 2)) : 0;
    constexpr int SME = (D * STG > TRE) ? (D * STG) : TRE;
    __shared__ __align__(16) unsigned short smem[SME];
    const int tid = threadIdx.x, lane = tid & 63;
    const int wm = tid >> 7, wn = (tid >> 6) & 1;
    const int bm = blockIdx.x * BM, bn = blockIdx.y * BM;
    const unsigned short* P[2] = {Pa, Pb};
    const unsigned short* Q[2] = {Qa, Qb};
    const unsigned short* sp[PA][TM];
    const unsigned short* sq[PB][TM];
    int dst[TM];
    #pragma unroll
    for (int it = 0; it < TM; ++it) {
        int s = tid + it * 256;
        int row = s >> 3, c = (s & 7) ^ (row & 7);
        dst[it] = (s - lane) * 8;
        #pragma unroll
        for (int p = 0; p < PA; ++p)
            sp[p][it] = P[p] + (size_t)perm[bm + row] * ns + 8 * c;
        #pragma unroll
        for (int p = 0; p < PB; ++p)
            sq[p][it] = Q[p] + (size_t)perm[bn + row] * ns + 8 * c;
    }
    f32x4 acc[TM][TM] = {};
    const int l15 = lane & 15, kb = lane >> 4;
    const int nt = K >> 6;

    auto stage = [&](int b, int koff) {
        unsigned short* base = smem + b * STG;
        #pragma unroll
        for (int p = 0; p < PA; ++p)
            #pragma unroll
            for (int it = 0; it < TM; ++it)
                gload_lds16(sp[p][it] + koff, base + p * PS + dst[it]);
        #pragma unroll
        for (int p = 0; p < PB; ++p)
            #pragma unroll
            for (int it = 0; it < TM; ++it)
                gload_lds16(sq[p][it] + koff, base + PA * PS + p * PS + dst[it]);
    };
    auto compute = [&](int b) {
        const unsigned short* base = smem + b * STG;
        #pragma unroll
        for (int h = 0; h < 2; ++h) {
            s16x8 av[PA][TM], bv[PB][TM];
            #pragma unroll
            for (int p = 0; p < PA; ++p)
                #pragma unroll
                for (int mi = 0; mi < TM; ++mi) {
                    int row = wm * (TM * 16) + mi * 16 + l15;
                    int slot = (h * 4 + kb) ^ (row & 7);
                    av[p][mi] = *(const s16x8*)(base + p * PS + row * 64 + slot * 8);
                }
            #pragma unroll
            for (int p = 0; p < PB; ++p)
                #pragma unroll
                for (int ni = 0; ni < TM; ++ni) {
                    int row = wn * (TM * 16) + ni * 16 + l15;
                    int slot = (h * 4 + kb) ^ (row & 7);
                    bv[p][ni] = *(const s16x8*)(base + PA * PS + p * PS + row * 64 + slot * 8);
                }
            #pragma unroll
            for (int mi = 0; mi < TM; ++mi)
                #pragma unroll
                for (int ni = 0; ni < TM; ++ni)
                    #pragma unroll
                    for (int pa = 0; pa < PA; ++pa)
                        #pragma unroll
                        for (int pb = 0; pb < PB; ++pb)
                            acc[mi][ni] = __builtin_amdgcn_mfma_f32_16x16x32_bf16(
                                av[pa][mi], bv[pb][ni], acc[mi][ni], 0, 0, 0);
        }
    };

    for (int i = 0; i < D - 1; ++i) stage(i, i * 64);
    for (int t = 0; t < nt; ++t) {
        const int ahead = nt - 1 - t;
        if (ahead >= D - 1) {
            stage((t + D - 1) % D, (t + D - 1) * 64);
            waitvm<2 * LPS>();
        } else if (ahead == 1) {
            waitvm<LPS>();
        } else {
            waitvm<0>();
        }
        __builtin_amdgcn_sched_barrier(0);
        __builtin_amdgcn_s_barrier();
        compute(t % D);
        __builtin_amdgcn_s_barrier();
    }

    const int hi = lane >> 4;
    #pragma unroll
    for (int mi = 0; mi < TM; ++mi)
        #pragma unroll
        for (int r = 0; r < 4; ++r) {
            int row = bm + wm * (TM * 16) + mi * 16 + hi * 4 + r;
            float s = 0.f;
            #pragma unroll
            for (int ni = 0; ni < TM; ++ni) {
                int col = bn + wn * (TM * 16) + ni * 16 + l15;
                float v = (row < kk && col < kk) ? ((row == col) ? 1.f : acc[mi][ni][r]) : 0.f;
                s += v;
                unsigned short h0 = f2bf(v);
                size_t o = (size_t)row * kp + col;
                H0[o] = h0;
                if (NP > 1) {
                    float r1 = v - bf2f(h0);
                    unsigned short h1 = f2bf(r1);
                    H1[o] = h1;
                    if (NP > 2) H2[o] = f2bf(r1 - bf2f(h1));
                }
            }
            #pragma unroll
            for (int m = 1; m < 16; m <<= 1) s += __shfl_xor(s, m);
            if (l15 == 0) atomicAdd(&dsum[row], s);
        }

    if (NT > 0) {
        #pragma unroll
        for (int pass = 0; pass < NT; ++pass) {
            __syncthreads();
            #pragma unroll
            for (int mi = 0; mi < TM; ++mi)
                #pragma unroll
                for (int ni = 0; ni < TM; ++ni)
                    #pragma unroll
                    for (int r = 0; r < 4; ++r) {
                        int rl = wm * (TM * 16) + mi * 16 + hi * 4 + r;
                        int cl = wn * (TM * 16) + ni * 16 + l15;
                        int row = bm + rl, col = bn + cl;
                        float v = (row < kk && col < kk) ? ((row == col) ? 1.f : acc[mi][ni][r]) : 0.f;
                        unsigned short h0 = f2bf(v);
                        unsigned short hv = h0;
                        if (pass == 1) hv = f2bf(v - bf2f(h0));
                        smem[rl * (BM + 2) + cl] = hv;
                    }
            __syncthreads();
            unsigned short* T = pass ? T1 : T0;
            #pragma unroll
            for (int e = 0; e < BM * BM / 256; ++e) {
                int idx = tid + e * 256;
                int j = idx / BM, i = idx & (BM - 1);
                T[(size_t)(bn + j) * kp + (bm + i)] = smem[i * (BM + 2) + j];
            }
        }
    }
}

template<int PA>
__global__ __launch_bounds__(256) void k_gcn_gemm(
    const unsigned short* __restrict__ Aa, const unsigned short* __restrict__ Ab,
    const unsigned short* __restrict__ Ac,
    const unsigned short* __restrict__ B0, const unsigned short* __restrict__ B1,
    const unsigned short* __restrict__ B2,
    int np, int kchunk, float* __restrict__ Zp)
{
    __shared__ __align__(16) unsigned short la[PA * 4096];
    __shared__ __align__(16) unsigned short lb[3 * 4096];
    const int tid = threadIdx.x, lane = tid & 63, wv = tid >> 6;
    const int bm = blockIdx.x * 64;
    const int kbeg = blockIdx.y * kchunk;
    const unsigned short* A[3] = {Aa, Ab, Ac};
    const unsigned short* B[3] = {B0, B1, B2};
    const unsigned short* sa[PA][2];
    const unsigned short* sb[3][2];
    int dst[2];
    #pragma unroll
    for (int it = 0; it < 2; ++it) {
        int s = tid + it * 256;
        int row = s >> 3, c = (s & 7) ^ (row & 7);
        dst[it] = (s - lane) * 8;
        #pragma unroll
        for (int p = 0; p < PA; ++p)
            sa[p][it] = A[p] + (size_t)(bm + row) * np + kbeg + 8 * c;
        #pragma unroll
        for (int p = 0; p < 3; ++p)
            sb[p][it] = B[p] + (size_t)row * np + kbeg + 8 * c;
    }
    f32x4 acc[4] = {};
    const int l15 = lane & 15, kb = lane >> 4;
    const int nt = kchunk >> 6;

    for (int tt = 0; tt < nt; ++tt) {
        if (tt) __syncthreads();
        int koff = tt * 64;
        #pragma unroll
        for (int p = 0; p < PA; ++p)
            #pragma unroll
            for (int it = 0; it < 2; ++it)
                gload_lds16(sa[p][it] + koff, &la[p * 4096 + dst[it]]);
        #pragma unroll
        for (int p = 0; p < 3; ++p)
            #pragma unroll
            for (int it = 0; it < 2; ++it)
                gload_lds16(sb[p][it] + koff, &lb[p * 4096 + dst[it]]);
        __syncthreads();
        #pragma unroll
        for (int h = 0; h < 2; ++h) {
            s16x8 av[PA], bv[3][4];
            #pragma unroll
            for (int p = 0; p < PA; ++p) {
                int row = wv * 16 + l15;
                int slot = (h * 4 + kb) ^ (row & 7);
                av[p] = *(const s16x8*)&la[p * 4096 + row * 64 + slot * 8];
            }
            #pragma unroll
            for (int p = 0; p < 3; ++p)
                #pragma unroll
                for (int ni = 0; ni < 4; ++ni) {
                    int row = ni * 16 + l15;
                    int slot = (h * 4 + kb) ^ (row & 7);
                    bv[p][ni] = *(const s16x8*)&lb[p * 4096 + row * 64 + slot * 8];
                }
            #pragma unroll
            for (int ni = 0; ni < 4; ++ni)
                #pragma unroll
                for (int pa = 0; pa < PA; ++pa)
                    #pragma unroll
                    for (int pb = 0; pb <= 2 - pa; ++pb)
                        acc[ni] = __builtin_amdgcn_mfma_f32_16x16x32_bf16(
                            av[pa], bv[pb][ni], acc[ni], 0, 0, 0);
        }
    }

    const int l4 = lane >> 4;
    float* Z = Zp + (size_t)blockIdx.y * np * 64;
    for (int ni = 0; ni < 4; ++ni)
        #pragma unroll
        for (int r = 0; r < 4; ++r) {
            int row = bm + wv * 16 + l4 * 4 + r;
            Z[(size_t)row * 64 + ni * 16 + l15] = acc[ni][r];
        }
}

// out = relu?( dis_i * (sum Z + (diag+1)*Y_i) + b ), dis inline
__global__ void k_gcn_epi(const float* __restrict__ Zp, const float* __restrict__ Y,
                          const float* __restrict__ dsum, const float* __restrict__ diagv,
                          const float* __restrict__ b, int n, int np, int nout, int relu,
                          int S, float* __restrict__ xo) {
    int t = blockIdx.x * blockDim.x + threadIdx.x;
    if (t >= n * 64) return;
    int i = t >> 6, f = t & 63;
    float s = 0.f;
    for (int kq = 0; kq < S; ++kq) s += Zp[(size_t)kq * np * 64 + t];
    float coef = 1.f + (diagv ? diagv[i] : 0.f);
    float v = disv(dsum, diagv, i) * (s + coef * Y[t]) + (f < nout ? b[f] : 0.f);
    if (relu) v = fmaxf(v, 0.f);
    xo[t] = v;
}

// final epilogue: logits (nout=3, no relu) + row softmax, one thread per row
__global__ void k_gcn_epi_sm(const float* __restrict__ Zp, const float* __restrict__ Y,
                             const float* __restrict__ dsum, const float* __restrict__ diagv,
                             const float* __restrict__ b, int n, int np, int S,
                             float* __restrict__ out) {
    int i = blockIdx.x * blockDim.x + threadIdx.x;
    if (i >= n) return;
    float dis = disv(dsum, diagv, i);
    float coef = 1.f + (diagv ? diagv[i] : 0.f);
    float v[3];
    #pragma unroll
    for (int f = 0; f < 3; ++f) {
        int t = i * 64 + f;
        float s = 0.f;
        for (int kq = 0; kq < S; ++kq) s += Zp[(size_t)kq * np * 64 + t];
        v[f] = dis * (s + coef * Y[t]) + b[f];
    }
    float m = fmaxf(v[0], fmaxf(v[1], v[2]));
    float e0 = expf(v[0] - m), e1 = expf(v[1] - m), e2 = expf(v[2] - m);
    float sum = e0 + e1 + e2;
    out[i * 3] = e0 / sum; out[i * 3 + 1] = e1 / sum; out[i * 3 + 2] = e2 / sum;
}

// ---------------- launch ----------------

extern "C" void kernel_launch(void* const* d_in, const int* in_sizes, int n_in,
                              void* d_out, int out_size, void* d_ws, size_t ws_size,
                              hipStream_t stream) {
    const int N0 = 3072;
    const int E = in_sizes[1] / 2;
    const int CIN = in_sizes[0] / N0;

    const float* x_in = (const float*)d_in[0];
    const int*   eidx = (const int*)d_in[1];
    const float* Wd0 = (const float*)d_in[2];  const float* bd0 = (const float*)d_in[3];
    const float* Wd1 = (const float*)d_in[4];  const float* bd1 = (const float*)d_in[5];
    const float* Wd2 = (const float*)d_in[6];  const float* bd2 = (const float*)d_in[7];
    const float* Wd3 = (const float*)d_in[8];  const float* bd3 = (const float*)d_in[9];
    const float* p1  = (const float*)d_in[10]; const float* p2  = (const float*)d_in[11];
    const float* p3  = (const float*)d_in[12];
    const float* Wu0 = (const float*)d_in[13]; const float* bu0 = (const float*)d_in[14];
    const float* Wu1 = (const float*)d_in[15]; const float* bu1 = (const float*)d_in[16];
    const float* Wu2 = (const float*)d_in[17]; const float* bu2 = (const float*)d_in[18];
    float* out = (float*)d_out;

    char* ws = (char*)d_ws;
    size_t off = 0;
    auto alloc = [&](size_t bytes) -> void* {
        off = (off + 255) & ~(size_t)255;
        void* p = ws + off;
        off += bytes;
        return p;
    };

    unsigned short* A0H  = (unsigned short*)alloc((size_t)3072 * 3072 * 2);
    unsigned char*  A0F8 = (unsigned char*)alloc((size_t)3072 * 3072);
    unsigned char*  A0T8 = (unsigned char*)alloc((size_t)3072 * 3072);
    float* d0   = (float*)alloc(3072 * 4);
    float* x0   = (float*)alloc((size_t)3072 * 64 * 4);
    unsigned short* P1H = (unsigned short*)alloc((size_t)2048 * 2048 * 2);
    unsigned short* P1T = (unsigned short*)alloc((size_t)2048 * 2048 * 2);
    float* x1   = (float*)alloc((size_t)2048 * 64 * 4);
    float* xp1  = (float*)alloc((size_t)2048 * 64 * 4);
    unsigned short* P2H  = (unsigned short*)alloc((size_t)1024 * 1024 * 2);
    unsigned short* P2L  = (unsigned short*)alloc((size_t)1024 * 1024 * 2);
    unsigned short* P2TH = (unsigned short*)alloc((size_t)1024 * 1024 * 2);
    unsigned short* P2TL = (unsigned short*)alloc((size_t)1024 * 1024 * 2);
    float* x2   = (float*)alloc((size_t)1024 * 64 * 4);
    float* xp2  = (float*)alloc((size_t)1024 * 64 * 4);
    unsigned short* P3a = (unsigned short*)alloc((size_t)512 * 512 * 2);
    unsigned short* P3b = (unsigned short*)alloc((size_t)512 * 512 * 2);
    unsigned short* P3c = (unsigned short*)alloc((size_t)512 * 512 * 2);
    float* x3   = (float*)alloc((size_t)512 * 64 * 4);
    float* xp3  = (float*)alloc((size_t)512 * 64 * 4);
    int*   perm1 = (int*)alloc(2048 * 4);  float* sc1 = (float*)alloc(2048 * 4);
    int*   perm2 = (int*)alloc(1024 * 4);  float* sc2 = (float*)alloc(1024 * 4);
    int*   perm3 = (int*)alloc(512 * 4);   float* sc3 = (float*)alloc(512 * 4);
    float* Yf  = (float*)alloc((size_t)3072 * 64 * 4);
    unsigned short* Yt0 = (unsigned short*)alloc((size_t)64 * 3072 * 2);
    unsigned short* Yt1 = (unsigned short*)alloc((size_t)64 * 3072 * 2);
    unsigned short* Yt2 = (unsigned short*)alloc((size_t)64 * 3072 * 2);
    float* Zp   = (float*)alloc((size_t)16 * 3072 * 64 * 4);
    // zeroed-each-launch region: dsum0..3 + rank1..3 + A0f contiguous (ONE memset)
    float* dsum0 = (float*)alloc(3072 * 4);
    float* dsum1 = (float*)alloc(2048 * 4);
    float* dsum2 = (float*)alloc(1024 * 4);
    float* dsum3 = (float*)alloc(512 * 4);
    int* rank1 = (int*)alloc(3072 * 4);
    int* rank2 = (int*)alloc(2048 * 4);
    int* rank3 = (int*)alloc(1024 * 4);
    char* scratch = (char*)alloc((size_t)3072 * 3072 * 4);
    if (off > ws_size) return;

    float* A0f = (float*)scratch;

    auto gcn = [&](const float* xin, int cin, const float* W, int ldw, int nout, const float* bias,
                   const unsigned short* Pa, const unsigned short* Pb2, const unsigned short* Pc,
                   int PA, int n, int np2, const float* dsum, const float* diagv,
                   const float* xc, const int* rank, int kpool, int relu, float* xout) {
        k_xw<<<DIVUP(np2 * 64, 256), 256, 0, stream>>>(xin, W, dsum, diagv, xc, rank, kpool,
                                                       n, np2, cin, ldw, nout, Yf, Yt0, Yt1, Yt2);
        int S = (np2 == 1024) ? 16 : 8;
        int kch = np2 / S;
        dim3 gg(np2 / 64, S);
        if (PA == 1)      k_gcn_gemm<1><<<gg, 256, 0, stream>>>(Pa, Pa, Pa, Yt0, Yt1, Yt2, np2, kch, Zp);
        else if (PA == 2) k_gcn_gemm<2><<<gg, 256, 0, stream>>>(Pa, Pb2, Pb2, Yt0, Yt1, Yt2, np2, kch, Zp);
        else              k_gcn_gemm<3><<<gg, 256, 0, stream>>>(Pa, Pb2, Pc, Yt0, Yt1, Yt2, np2, kch, Zp);
        if (xout)
            k_gcn_epi<<<DIVUP(n * 64, 256), 256, 0, stream>>>(Zp, Yf, dsum, diagv, bias, n, np2, nout, relu, S, xout);
        else
            k_gcn_epi_sm<<<DIVUP(n, 256), 256, 0, stream>>>(Zp, Yf, dsum, diagv, bias, n, np2, S, out);
    };

    auto topk = [&](const float* x, const float* pvec, int n, int k, int kp,
                    int* rank, int* perm, float* scv, float* xo) {
        dim3 gr(DIVUP(n, 256), DIVUP(n, 256));
        k_count_rank<<<gr, 256, 0, stream>>>(x, pvec, rank, n);
        k_topk_finish<<<DIVUP(n, 256), 256, 0, stream>>>(x, pvec, rank, n, k, kp, perm, scv, xo);
    };

    // one memset: dsum0..rank3 + A0f (all zero-init, contiguous)
    hipMemsetAsync(dsum0, 0, ((char*)A0f + (size_t)3072 * 3072 * 4) - (char*)dsum0, stream);

    k_scatter<<<DIVUP(E, 256), 256, 0, stream>>>(eidx, A0f, E, N0);
    k_a0_plane<<<3072 * 3072 / 256, 256, 0, stream>>>(A0f, A0H, A0F8, d0, dsum0, N0);
    k_transpose_i8<<<dim3(48, 48), 256, 0, stream>>>(A0F8, A0T8, 3072);

    gcn(x_in, CIN, Wd0, 64, 64, bd0, A0H, A0H, A0H, 1, 3072, 3072, dsum0, d0,
        nullptr, nullptr, 0, 1, x0);

    topk(x0, p1, 3072, 2000, 2048, rank1, perm1, sc1, xp1);
    k_aug8<2><<<dim3(32, 32), 256, 0, stream>>>(
        A0F8, A0T8, perm1, 2000, 2048, 3072, 3072, P1H, P1T, dsum1);
    gcn(xp1, 64, Wd1, 64, 64, bd1, P1H, P1H, P1H, 1, 2000, 2048, dsum1, nullptr,
        nullptr, nullptr, 0, 1, x1);

    topk(x1, p2, 2000, 1000, 1024, rank2, perm2, sc2, xp2);
    k_aug2<2, 1, 1, 2, 2><<<dim3(16, 16), 256, 0, stream>>>(
        P1H, P1H, P1T, P1T, perm2, 1000, 1024, 2048, 2048, P2H, P2L, P2L, P2TH, P2TL, dsum2);
    gcn(xp2, 64, Wd2, 64, 64, bd2, P2H, P2L, P2L, 2, 1000, 1024, dsum2, nullptr,
        nullptr, nullptr, 0, 1, x2);

    topk(x2, p3, 1000, 500, 512, rank3, perm3, sc3, xp3);
    k_aug2<2, 2, 2, 3, 0><<<dim3(8, 8), 256, 0, stream>>>(
        P2H, P2L, P2TH, P2TL, perm3, 500, 512, 1024, 1024, P3a, P3b, P3c, nullptr, nullptr, dsum3);
    gcn(xp3, 64, Wd3, 64, 64, bd3, P3a, P3b, P3c, 3, 500, 512, dsum3, nullptr,
        nullptr, nullptr, 0, 1, x3);

    // up 0: res=x2 + unpool(x3 via rank3)
    gcn(x2, 64, Wu0, 64, 64, bu0, P2H, P2L, P2L, 2, 1000, 1024, dsum2, nullptr,
        x3, rank3, 500, 1, xp2);

    // up 1: res=x1 + unpool(xp2 via rank2)
    gcn(x1, 64, Wu1, 64, 64, bu1, P1H, P1H, P1H, 1, 2000, 2048, dsum1, nullptr,
        xp2, rank2, 1000, 1, xp1);

    // up 2: res=x0 + unpool(xp1 via rank1), logits+softmax fused
    gcn(x0, 64, Wu2, 3, 3, bu2, A0H, A0H, A0H, 1, 3072, 3072, dsum0, d0,
        xp1, rank1, 2000, 0, nullptr);
}